// Round 7
// baseline (554.974 us; speedup 1.0000x reference)
//
#include <hip/hip_runtime.h>
#include <hip/hip_bf16.h>
#include <math.h>

#define DIMD   1024
#define NBATCH 4
#define NSEQ   8192
#define NTOK   (NBATCH * NSEQ)
#define NHEAVY 1024
#define NSEL   (NBATCH * NHEAVY)
#define DLIGHT 512
#define DHEAVY 4096
#define NITERS 50

typedef __attribute__((ext_vector_type(8))) short short8;
typedef __attribute__((ext_vector_type(4))) float f32x4;

__device__ __forceinline__ unsigned short f2bf(float f) {
    __hip_bfloat16 h = __float2bfloat16(f);
    union { __hip_bfloat16 h; unsigned short u; } cvt;
    cvt.h = h;
    return cvt.u;
}

// Abramowitz-Stegun 7.1.26 erf, |eps|<=1.5e-7, single path (no branches).
__device__ __forceinline__ float gelu_fast(float x) {
    float ax = fabsf(x) * 0.7071067811865475f;
    float t = 1.0f / fmaf(0.3275911f, ax, 1.0f);
    float p = fmaf(t, 1.061405429f, -1.453152027f);
    p = fmaf(t, p, 1.421413741f);
    p = fmaf(t, p, -0.284496736f);
    p = fmaf(t, p, 0.254829592f);
    p = p * t;
    float e = __expf(-ax * ax);
    float erf_abs = fmaf(-p, e, 1.0f);
    float erf = copysignf(erf_abs, x);
    return 0.5f * x * (1.0f + erf);
}

__device__ __forceinline__ void gload_lds16(const void* g, void* l) {
    __builtin_amdgcn_global_load_lds(
        (const __attribute__((address_space(1))) void*)g,
        (__attribute__((address_space(3))) void*)l,
        16, 0, 0);
}

// in[K][N] f32 -> out[N][K] bf16, optionally scaling row k by gamma[k].
__global__ void cvt_transpose(const float* __restrict__ in, __hip_bfloat16* __restrict__ out,
                              int K, int N, const float* __restrict__ gamma) {
    __shared__ float tile[32][33];
    int n0 = blockIdx.x * 32, k0 = blockIdx.y * 32;
    int tx = threadIdx.x, ty = threadIdx.y;  // (32, 8)
    #pragma unroll
    for (int j = 0; j < 4; j++) {
        int k = k0 + ty + 8 * j;
        float g = gamma ? gamma[k] : 1.0f;
        tile[ty + 8 * j][tx] = in[(size_t)k * N + (n0 + tx)] * g;
    }
    __syncthreads();
    #pragma unroll
    for (int j = 0; j < 4; j++)
        out[(size_t)(n0 + ty + 8 * j) * K + (k0 + tx)] = __float2bfloat16(tile[tx][ty + 8 * j]);
}

// One block per token: xb = bf16(x_row); sc = 32/max(||x||,1e-12);
// s = dot(x_row, rt) in f64 (same reduction order as prior rounds).
__global__ void xpass_kern(const float* __restrict__ x, const float* __restrict__ rt,
                           unsigned short* __restrict__ xb, float* __restrict__ sc,
                           double* __restrict__ s_out) {
    int t = blockIdx.x;
    int tid = threadIdx.x;  // 256
    const float4* xr = (const float4*)(x + (size_t)t * DIMD);
    float4 v = xr[tid];
    // bf16 store, 8B per lane contiguous
    ushort4 pk;
    pk.x = f2bf(v.x); pk.y = f2bf(v.y); pk.z = f2bf(v.z); pk.w = f2bf(v.w);
    ((ushort4*)(xb + (size_t)t * DIMD))[tid] = pk;

    float ss = v.x * v.x + v.y * v.y + v.z * v.z + v.w * v.w;
    float4 rv = ((const float4*)rt)[tid];
    double sd = (double)v.x * rv.x + (double)v.y * rv.y + (double)v.z * rv.z + (double)v.w * rv.w;
    #pragma unroll
    for (int off = 32; off > 0; off >>= 1) {
        ss += __shfl_down(ss, off);
        sd += __shfl_down(sd, off);
    }
    __shared__ float red[4];
    __shared__ double redd[4];
    if ((tid & 63) == 0) { red[tid >> 6] = ss; redd[tid >> 6] = sd; }
    __syncthreads();
    if (tid == 0) {
        s_out[t] = redd[0] + redd[1] + redd[2] + redd[3];
        float tot = red[0] + red[1] + red[2] + red[3];
        sc[t] = 32.0f / fmaxf(sqrtf(tot), 1e-12f);
    }
}

// 50-step coordinate descent per batch row, f64.
__global__ void descent_kern(const double* __restrict__ s, double* __restrict__ a_out) {
    int r = blockIdx.x, tid = threadIdx.x;  // 1024 threads
    const double* sr = s + (size_t)r * NSEQ;
    double es[8];
    #pragma unroll
    for (int i = 0; i < 8; i++) es[i] = exp(sr[tid + i * 1024]);
    __shared__ double red[2][16];
    const double logk = log(1152.0);  // min(1024 * 9/8, 8192)
    double a = logk - log((double)NSEQ);
    for (int it = 1; it < NITERS; it++) {
        double ea = exp(a);
        double loc = 0.0;
        #pragma unroll
        for (int i = 0; i < 8; i++) {
            double p = es[i] * ea;
            loc += (p < 1.0 ? p : 1.0);
        }
        #pragma unroll
        for (int off = 32; off > 0; off >>= 1) loc += __shfl_down(loc, off);
        int pb = it & 1;
        if ((tid & 63) == 0) red[pb][tid >> 6] = loc;
        __syncthreads();
        double S = 0.0;
        #pragma unroll
        for (int i = 0; i < 16; i++) S += red[pb][i];
        a = logk + a - log(S);
    }
    if (tid == 0) a_out[r] = a;
}

// Selection per batch row (1 wave): tokens with s+a>=0 (plateau, lowest-index
// tie-break), fill by descending s. Also writes inv[token] = heavy slot.
__global__ void select_kern(const double* __restrict__ s, const double* __restrict__ a_arr,
                            int* __restrict__ sel, int* __restrict__ inv) {
    int r = blockIdx.x, l = threadIdx.x;  // 64 threads
    const double* sr = s + (size_t)r * NSEQ;
    double a = a_arr[r];
    __shared__ double sw[NSEQ];  // 64 KB
    int cnt = 0;
    for (int base = 0; base < NSEQ; base += 64) {
        int idx = base + l;
        double v = sr[idx];
        bool sat = (v + a) >= 0.0;
        sw[idx] = sat ? -1.0e300 : v;
        unsigned long long m = __ballot(sat);
        int pre = __popcll(m & ((1ull << l) - 1ull));
        if (sat) {
            int slot = cnt + pre;
            if (slot < NHEAVY) {
                sel[r * NHEAVY + slot] = r * NSEQ + idx;
                inv[r * NSEQ + idx] = r * NHEAVY + slot;
            }
        }
        cnt += (int)__popcll(m);
    }
    __syncthreads();
    for (int slot = cnt; slot < NHEAVY; slot++) {  // rarely taken fallback
        double best = -1.0e301; int bidx = NSEQ;
        for (int i = 0; i < NSEQ / 64; i++) {
            int idx = i * 64 + l;
            double v = sw[idx];
            if (v > best) { best = v; bidx = idx; }
        }
        #pragma unroll
        for (int off = 32; off > 0; off >>= 1) {
            double ov = __shfl_down(best, off);
            int oi = __shfl_down(bidx, off);
            if (ov > best || (ov == best && oi < bidx)) { best = ov; bidx = oi; }
        }
        bidx = __shfl(bidx, 0);
        if (l == 0) {
            sel[r * NHEAVY + slot] = r * NSEQ + bidx;
            inv[r * NSEQ + bidx] = r * NHEAVY + slot;
            sw[bidx] = -1.0e300;
        }
        __syncthreads();
    }
}

// C[M,N] = A[M,K]*Bt[N,K]^T, bf16 in / f32 acc. 128x128 tile, BK=64, 4 waves.
// GATHER: A row r comes from A + sel[r]*K (per-lane global src, linear LDS dst).
// EPI 0: bf16 out = gelu(sc_row*acc + bias)    (GEMM1s; sc_row via sel if GATHER)
// EPI 2: bf16 partial[bz][m][n] = acc          (heavy GEMM2 split-K, no bias)
// EPI 3: f32 out = acc + bias [+ bias2 + sum_j phb[j][inv[row]]]  (light GEMM2 fused)
template <int EPI, bool GATHER>
__global__ __launch_bounds__(256) void gemm_bt(
    const short* __restrict__ A, const short* __restrict__ Bt,
    const float* __restrict__ bias, const float* __restrict__ bias2,
    const float* __restrict__ sc, const int* __restrict__ sel,
    const int* __restrict__ inv, const __hip_bfloat16* __restrict__ phb, int nsk,
    float* __restrict__ outf, __hip_bfloat16* __restrict__ outb,
    int M, int N, int K) {
    __shared__ alignas(16) short As[128 * 64];
    __shared__ alignas(16) short Bs[128 * 64];
    // bijective XCD-aware swizzle on the flattened block id (m157/m204)
    int nx = gridDim.x, ny = gridDim.y;
    int nwg = nx * ny * gridDim.z;
    int id = ((int)blockIdx.z * ny + blockIdx.y) * nx + blockIdx.x;
    if ((nwg & 7) == 0) id = (id & 7) * (nwg >> 3) + (id >> 3);
    int bxi = id % nx; int rem = id / nx;
    int byi = rem % ny; int bz = rem / ny;
    int klen = K / (int)gridDim.z, k_start = bz * klen;

    int tid = threadIdx.x;
    int l = tid & 63, w = tid >> 6;
    int wr = w >> 1, wc = w & 1;
    int bn0 = bxi * 128, bm0 = byi * 128;

    f32x4 zero = {0.f, 0.f, 0.f, 0.f};
    f32x4 acc[4][4];
    #pragma unroll
    for (int i = 0; i < 4; i++)
        #pragma unroll
        for (int j = 0; j < 4; j++) acc[i][j] = zero;

    const int lrow = l & 15, lk = (l >> 4) * 8;
    int srow = tid >> 3, scol = (tid & 7) * 8;
    const short* AgC[4];
    #pragma unroll
    for (int c = 0; c < 4; c++) {
        int rr = bm0 + srow + c * 32;
        int gr = GATHER ? sel[rr] : rr;
        AgC[c] = A + (size_t)gr * K + scol;
    }
    const short* Bg = Bt + (size_t)(bn0 + srow) * K + scol;
    short* Asb = As + (tid & ~63) * 8;  // wave-uniform LDS base (+lane*16B by HW)
    short* Bsb = Bs + (tid & ~63) * 8;

    for (int k0 = k_start; k0 < k_start + klen; k0 += 64) {
        #pragma unroll
        for (int c = 0; c < 4; c++) {
            gload_lds16(AgC[c] + k0, Asb + c * 2048);
            gload_lds16(Bg + (size_t)(c * 32) * K + k0, Bsb + c * 2048);
        }
        __syncthreads();  // compiler drains vmcnt before barrier
        #pragma unroll
        for (int kk = 0; kk < 2; kk++) {
            short8 af[4], bf[4];
            #pragma unroll
            for (int i = 0; i < 4; i++) {
                af[i] = *reinterpret_cast<const short8*>(&As[(wr * 64 + i * 16 + lrow) * 64 + kk * 32 + lk]);
                bf[i] = *reinterpret_cast<const short8*>(&Bs[(wc * 64 + i * 16 + lrow) * 64 + kk * 32 + lk]);
            }
            #pragma unroll
            for (int mi = 0; mi < 4; mi++)
                #pragma unroll
                for (int ni = 0; ni < 4; ni++)
                    acc[mi][ni] = __builtin_amdgcn_mfma_f32_16x16x32_bf16(af[mi], bf[ni], acc[mi][ni], 0, 0, 0);
        }
        __syncthreads();
    }

    int orow0 = bm0 + wr * 64, ocol0 = bn0 + wc * 64;
    #pragma unroll
    for (int mi = 0; mi < 4; mi++) {
        int rowb = orow0 + mi * 16 + (l >> 4) * 4;
        float scv[4];
        int ivv[4];
        #pragma unroll
        for (int rg = 0; rg < 4; rg++) {
            if (EPI == 0) {
                int r = rowb + rg;
                scv[rg] = sc[GATHER ? sel[r] : r];
            } else if (EPI == 3) {
                ivv[rg] = inv[rowb + rg];
            }
        }
        #pragma unroll
        for (int ni = 0; ni < 4; ni++) {
            int col = ocol0 + ni * 16 + (l & 15);
            float bv = (EPI == 2) ? 0.0f : bias[col];
            #pragma unroll
            for (int rg = 0; rg < 4; rg++) {
                int row = rowb + rg;
                if (EPI == 0) {
                    float v = fmaf(scv[rg], acc[mi][ni][rg], bv);
                    outb[(size_t)row * N + col] = __float2bfloat16(gelu_fast(v));
                } else if (EPI == 2) {
                    outb[((size_t)bz * M + row) * (size_t)N + col] = __float2bfloat16(acc[mi][ni][rg]);
                } else {  // EPI == 3
                    float v = acc[mi][ni][rg] + bv;
                    int iv = ivv[rg];
                    if (iv >= 0) {
                        float hs = bias2[col];
                        for (int j = 0; j < nsk; j++)
                            hs += __bfloat162float(phb[((size_t)j * NSEL + iv) * DIMD + col]);
                        v += hs;
                    }
                    outf[(size_t)row * N + col] = v;
                }
            }
        }
    }
}

extern "C" void kernel_launch(void* const* d_in, const int* in_sizes, int n_in,
                              void* d_out, int out_size, void* d_ws, size_t ws_size,
                              hipStream_t stream) {
    (void)in_sizes; (void)n_in; (void)out_size;
    const float* x      = (const float*)d_in[0];
    const float* rt     = (const float*)d_in[1];
    const float* lgamma = (const float*)d_in[2];
    const float* lw1    = (const float*)d_in[3];
    const float* lb1    = (const float*)d_in[4];
    const float* lw2    = (const float*)d_in[5];
    const float* lb2    = (const float*)d_in[6];
    const float* hgamma = (const float*)d_in[7];
    const float* hw1    = (const float*)d_in[8];
    const float* hb1    = (const float*)d_in[9];
    const float* hw2    = (const float*)d_in[10];
    const float* hb2    = (const float*)d_in[11];
    float* out = (float*)d_out;

    auto rnd = [](size_t b) { return (b + 255) & ~(size_t)255; };
    size_t fixed = rnd(NTOK * sizeof(double))        // s
                 + rnd(256)                          // a
                 + rnd(NSEL * sizeof(int))           // sel
                 + rnd(NTOK * sizeof(int))           // inv
                 + rnd(NTOK * sizeof(float))         // sc
                 + rnd((size_t)DLIGHT * DIMD * 2)    // wl1t
                 + rnd((size_t)DIMD * DLIGHT * 2)    // wl2t
                 + rnd((size_t)DHEAVY * DIMD * 2)    // wh1t
                 + rnd((size_t)DIMD * DHEAVY * 2)    // wh2t
                 + rnd((size_t)NTOK * DIMD * 2)      // xb
                 + rnd((size_t)NSEL * DHEAVY * 2);   // hh (aliased by hl)
    int nsk = 4;
    while (nsk > 1 && fixed + rnd((size_t)nsk * NSEL * DIMD * 2) > ws_size) nsk >>= 1;

    char* base = (char*)d_ws;
    size_t off = 0;
    auto alloc = [&](size_t bytes) -> void* {
        void* p = base + off;
        off += rnd(bytes);
        return p;
    };
    double* s     = (double*)alloc(NTOK * sizeof(double));
    double* a_arr = (double*)alloc(256);
    int*    sel   = (int*)alloc(NSEL * sizeof(int));
    int*    inv   = (int*)alloc(NTOK * sizeof(int));
    float*  sc    = (float*)alloc(NTOK * sizeof(float));
    short*  wl1t  = (short*)alloc((size_t)DLIGHT * DIMD * 2);
    short*  wl2t  = (short*)alloc((size_t)DIMD * DLIGHT * 2);
    short*  wh1t  = (short*)alloc((size_t)DHEAVY * DIMD * 2);
    short*  wh2t  = (short*)alloc((size_t)DIMD * DHEAVY * 2);
    short*  xb    = (short*)alloc((size_t)NTOK * DIMD * 2);
    short*  hh    = (short*)alloc((size_t)NSEL * DHEAVY * 2);
    short*  hl    = hh;  // light GEMM1 output aliases hh (dead after heavy GEMM2)
    short*  phb   = (short*)alloc((size_t)nsk * NSEL * DIMD * 2);

    // weights -> bf16 [N][K]; gamma folded into W1 rows
    cvt_transpose<<<dim3(DLIGHT / 32, DIMD / 32), dim3(32, 8), 0, stream>>>(lw1, (__hip_bfloat16*)wl1t, DIMD, DLIGHT, lgamma);
    cvt_transpose<<<dim3(DIMD / 32, DLIGHT / 32), dim3(32, 8), 0, stream>>>(lw2, (__hip_bfloat16*)wl2t, DLIGHT, DIMD, nullptr);
    cvt_transpose<<<dim3(DHEAVY / 32, DIMD / 32), dim3(32, 8), 0, stream>>>(hw1, (__hip_bfloat16*)wh1t, DIMD, DHEAVY, hgamma);
    cvt_transpose<<<dim3(DIMD / 32, DHEAVY / 32), dim3(32, 8), 0, stream>>>(hw2, (__hip_bfloat16*)wh2t, DHEAVY, DIMD, nullptr);

    hipMemsetAsync(inv, 0xFF, NTOK * sizeof(int), stream);  // inv = -1

    // fused pass: xb=bf16(x), sc, router s
    xpass_kern<<<NTOK, 256, 0, stream>>>(x, rt, (unsigned short*)xb, sc, s);
    descent_kern<<<NBATCH, 1024, 0, stream>>>(s, a_arr);
    select_kern<<<NBATCH, 64, 0, stream>>>(s, a_arr, sel, inv);

    // heavy: GEMM1 (gather A-rows from xb, sc+gelu epi) -> hh; GEMM2 split-K -> phb
    gemm_bt<0, true><<<dim3(DHEAVY / 128, NSEL / 128), 256, 0, stream>>>(
        xb, wh1t, hb1, nullptr, sc, sel, nullptr, nullptr, 0,
        nullptr, (__hip_bfloat16*)hh, NSEL, DHEAVY, DIMD);
    gemm_bt<2, false><<<dim3(DIMD / 128, NSEL / 128, nsk), 256, 0, stream>>>(
        hh, wh2t, nullptr, nullptr, nullptr, nullptr, nullptr, nullptr, 0,
        nullptr, (__hip_bfloat16*)phb, NSEL, DIMD, DHEAVY);

    // light: GEMM1 -> hl (aliases hh); GEMM2 fused (+heavy partials via inv) -> out
    gemm_bt<0, false><<<dim3(DLIGHT / 128, NTOK / 128), 256, 0, stream>>>(
        xb, wl1t, lb1, nullptr, sc, nullptr, nullptr, nullptr, 0,
        nullptr, (__hip_bfloat16*)hl, NTOK, DLIGHT, DIMD);
    gemm_bt<3, false><<<dim3(DIMD / 128, NTOK / 128), 256, 0, stream>>>(
        hl, wl2t, lb2, hb2, nullptr, nullptr, inv, (const __hip_bfloat16*)phb, nsk,
        out, nullptr, NTOK, DIMD, DLIGHT);
}

// Round 8
// 464.753 us; speedup vs baseline: 1.1941x; 1.1941x over previous
//
#include <hip/hip_runtime.h>
#include <hip/hip_bf16.h>
#include <math.h>

#define DIMD   1024
#define NBATCH 4
#define NSEQ   8192
#define NTOK   (NBATCH * NSEQ)
#define NHEAVY 1024
#define NSEL   (NBATCH * NHEAVY)
#define DLIGHT 512
#define DHEAVY 4096
#define NITERS 50

typedef __attribute__((ext_vector_type(8))) short short8;
typedef __attribute__((ext_vector_type(4))) float f32x4;
typedef __attribute__((ext_vector_type(4))) unsigned short u16x4;

__device__ __forceinline__ unsigned short f2bf(float f) {
    __hip_bfloat16 h = __float2bfloat16(f);
    union { __hip_bfloat16 h; unsigned short u; } cvt;
    cvt.h = h;
    return cvt.u;
}

__device__ __forceinline__ float bf2f(unsigned short u) {
    return __uint_as_float((unsigned)u << 16);
}

// Abramowitz-Stegun 7.1.26 erf, |eps|<=1.5e-7, single path (no branches).
__device__ __forceinline__ float gelu_fast(float x) {
    float ax = fabsf(x) * 0.7071067811865475f;
    float t = 1.0f / fmaf(0.3275911f, ax, 1.0f);
    float p = fmaf(t, 1.061405429f, -1.453152027f);
    p = fmaf(t, p, 1.421413741f);
    p = fmaf(t, p, -0.284496736f);
    p = fmaf(t, p, 0.254829592f);
    p = p * t;
    float e = __expf(-ax * ax);
    float erf_abs = fmaf(-p, e, 1.0f);
    float erf = copysignf(erf_abs, x);
    return 0.5f * x * (1.0f + erf);
}

__device__ __forceinline__ void gload_lds16(const void* g, void* l) {
    __builtin_amdgcn_global_load_lds(
        (const __attribute__((address_space(1))) void*)g,
        (__attribute__((address_space(3))) void*)l,
        16, 0, 0);
}

// in[K][N] f32 -> out[N][K] bf16, optionally scaling row k by gamma[k].
__global__ void cvt_transpose(const float* __restrict__ in, __hip_bfloat16* __restrict__ out,
                              int K, int N, const float* __restrict__ gamma) {
    __shared__ float tile[32][33];
    int n0 = blockIdx.x * 32, k0 = blockIdx.y * 32;
    int tx = threadIdx.x, ty = threadIdx.y;  // (32, 8)
    #pragma unroll
    for (int j = 0; j < 4; j++) {
        int k = k0 + ty + 8 * j;
        float g = gamma ? gamma[k] : 1.0f;
        tile[ty + 8 * j][tx] = in[(size_t)k * N + (n0 + tx)] * g;
    }
    __syncthreads();
    #pragma unroll
    for (int j = 0; j < 4; j++)
        out[(size_t)(n0 + ty + 8 * j) * K + (k0 + tx)] = __float2bfloat16(tile[tx][ty + 8 * j]);
}

// One block per token: xb = bf16(x_row); sc = 32/max(||x||,1e-12);
// s = dot(x_row, rt) in f64 (same reduction order as prior rounds).
__global__ void xpass_kern(const float* __restrict__ x, const float* __restrict__ rt,
                           unsigned short* __restrict__ xb, float* __restrict__ sc,
                           double* __restrict__ s_out) {
    int t = blockIdx.x;
    int tid = threadIdx.x;  // 256
    const float4* xr = (const float4*)(x + (size_t)t * DIMD);
    float4 v = xr[tid];
    ushort4 pk;
    pk.x = f2bf(v.x); pk.y = f2bf(v.y); pk.z = f2bf(v.z); pk.w = f2bf(v.w);
    ((ushort4*)(xb + (size_t)t * DIMD))[tid] = pk;

    float ss = v.x * v.x + v.y * v.y + v.z * v.z + v.w * v.w;
    float4 rv = ((const float4*)rt)[tid];
    double sd = (double)v.x * rv.x + (double)v.y * rv.y + (double)v.z * rv.z + (double)v.w * rv.w;
    #pragma unroll
    for (int off = 32; off > 0; off >>= 1) {
        ss += __shfl_down(ss, off);
        sd += __shfl_down(sd, off);
    }
    __shared__ float red[4];
    __shared__ double redd[4];
    if ((tid & 63) == 0) { red[tid >> 6] = ss; redd[tid >> 6] = sd; }
    __syncthreads();
    if (tid == 0) {
        s_out[t] = redd[0] + redd[1] + redd[2] + redd[3];
        float tot = red[0] + red[1] + red[2] + red[3];
        sc[t] = 32.0f / fmaxf(sqrtf(tot), 1e-12f);
    }
}

// 50-step coordinate descent per batch row, f64.
__global__ void descent_kern(const double* __restrict__ s, double* __restrict__ a_out) {
    int r = blockIdx.x, tid = threadIdx.x;  // 1024 threads
    const double* sr = s + (size_t)r * NSEQ;
    double es[8];
    #pragma unroll
    for (int i = 0; i < 8; i++) es[i] = exp(sr[tid + i * 1024]);
    __shared__ double red[2][16];
    const double logk = log(1152.0);  // min(1024 * 9/8, 8192)
    double a = logk - log((double)NSEQ);
    for (int it = 1; it < NITERS; it++) {
        double ea = exp(a);
        double loc = 0.0;
        #pragma unroll
        for (int i = 0; i < 8; i++) {
            double p = es[i] * ea;
            loc += (p < 1.0 ? p : 1.0);
        }
        #pragma unroll
        for (int off = 32; off > 0; off >>= 1) loc += __shfl_down(loc, off);
        int pb = it & 1;
        if ((tid & 63) == 0) red[pb][tid >> 6] = loc;
        __syncthreads();
        double S = 0.0;
        #pragma unroll
        for (int i = 0; i < 16; i++) S += red[pb][i];
        a = logk + a - log(S);
    }
    if (tid == 0) a_out[r] = a;
}

// Selection per batch row (1 wave): tokens with s+a>=0 (plateau, lowest-index
// tie-break), fill by descending s. Also writes inv[token] = heavy slot.
__global__ void select_kern(const double* __restrict__ s, const double* __restrict__ a_arr,
                            int* __restrict__ sel, int* __restrict__ inv) {
    int r = blockIdx.x, l = threadIdx.x;  // 64 threads
    const double* sr = s + (size_t)r * NSEQ;
    double a = a_arr[r];
    __shared__ double sw[NSEQ];  // 64 KB
    int cnt = 0;
    for (int base = 0; base < NSEQ; base += 64) {
        int idx = base + l;
        double v = sr[idx];
        bool sat = (v + a) >= 0.0;
        sw[idx] = sat ? -1.0e300 : v;
        unsigned long long m = __ballot(sat);
        int pre = __popcll(m & ((1ull << l) - 1ull));
        if (sat) {
            int slot = cnt + pre;
            if (slot < NHEAVY) {
                sel[r * NHEAVY + slot] = r * NSEQ + idx;
                inv[r * NSEQ + idx] = r * NHEAVY + slot;
            }
        }
        cnt += (int)__popcll(m);
    }
    __syncthreads();
    for (int slot = cnt; slot < NHEAVY; slot++) {  // rarely taken fallback
        double best = -1.0e301; int bidx = NSEQ;
        for (int i = 0; i < NSEQ / 64; i++) {
            int idx = i * 64 + l;
            double v = sw[idx];
            if (v > best) { best = v; bidx = idx; }
        }
        #pragma unroll
        for (int off = 32; off > 0; off >>= 1) {
            double ov = __shfl_down(best, off);
            int oi = __shfl_down(bidx, off);
            if (ov > best || (ov == best && oi < bidx)) { best = ov; bidx = oi; }
        }
        bidx = __shfl(bidx, 0);
        if (l == 0) {
            sel[r * NHEAVY + slot] = r * NSEQ + bidx;
            inv[r * NSEQ + bidx] = r * NHEAVY + slot;
            sw[bidx] = -1.0e300;
        }
        __syncthreads();
    }
}

// hv[h][c] = hb2[c] + sum_j phb[j][h][c]   (dense heavy-output reduce, f32)
__global__ __launch_bounds__(256) void reduce_hv_kern(
    const unsigned short* __restrict__ phb, const float* __restrict__ hb2,
    float* __restrict__ hv, int nsk) {
    int h = blockIdx.x;          // 0..NSEL-1
    int c0 = threadIdx.x * 4;    // 256 threads x 4 cols
    f32x4 acc = *reinterpret_cast<const f32x4*>(hb2 + c0);
    for (int j = 0; j < nsk; j++) {
        u16x4 p = *reinterpret_cast<const u16x4*>(phb + ((size_t)j * NSEL + h) * DIMD + c0);
        #pragma unroll
        for (int rg = 0; rg < 4; rg++) acc[rg] += bf2f(p[rg]);
    }
    *reinterpret_cast<f32x4*>(hv + (size_t)h * DIMD + c0) = acc;
}

// C[M,N] = A[M,K]*Bt[N,K]^T, bf16 in / f32 acc. 128x128 tile, BK=64, 4 waves.
// MFMA called operand-SWAPPED: mfma(bf, af) -> lane owns row=(l&15)+16*mi of C
// and 4 CONSECUTIVE cols (l>>4)*4 + reg -> vectorized stores.
// GATHER: A row r comes from A + sel[r]*K (per-lane global src, linear LDS dst).
// EPI 0: bf16 out = gelu(sc_row*acc + bias)      (GEMM1s)
// EPI 2: bf16 partial[bz][m][n] = acc            (heavy GEMM2 split-K, no bias)
// EPI 3: f32 out = acc + bias [+ hv[inv[row]]]   (light GEMM2 fused)
template <int EPI, bool GATHER>
__global__ __launch_bounds__(256) void gemm_bt(
    const short* __restrict__ A, const short* __restrict__ Bt,
    const float* __restrict__ bias,
    const float* __restrict__ sc, const int* __restrict__ sel,
    const int* __restrict__ inv, const float* __restrict__ hv,
    float* __restrict__ outf, __hip_bfloat16* __restrict__ outb,
    int M, int N, int K) {
    __shared__ alignas(16) short As[128 * 64];
    __shared__ alignas(16) short Bs[128 * 64];
    // bijective XCD-aware swizzle on the flattened block id (m157/m204)
    int nx = gridDim.x, ny = gridDim.y;
    int nwg = nx * ny * gridDim.z;
    int id = ((int)blockIdx.z * ny + blockIdx.y) * nx + blockIdx.x;
    if ((nwg & 7) == 0) id = (id & 7) * (nwg >> 3) + (id >> 3);
    int bxi = id % nx; int rem = id / nx;
    int byi = rem % ny; int bz = rem / ny;
    int klen = K / (int)gridDim.z, k_start = bz * klen;

    int tid = threadIdx.x;
    int l = tid & 63, w = tid >> 6;
    int wr = w >> 1, wc = w & 1;
    int bn0 = bxi * 128, bm0 = byi * 128;

    f32x4 zero = {0.f, 0.f, 0.f, 0.f};
    f32x4 acc[4][4];
    #pragma unroll
    for (int i = 0; i < 4; i++)
        #pragma unroll
        for (int j = 0; j < 4; j++) acc[i][j] = zero;

    const int lrow = l & 15, lk = (l >> 4) * 8;
    int srow = tid >> 3, scol = (tid & 7) * 8;
    const short* AgC[4];
    #pragma unroll
    for (int c = 0; c < 4; c++) {
        int rr = bm0 + srow + c * 32;
        int gr = GATHER ? sel[rr] : rr;
        AgC[c] = A + (size_t)gr * K + scol;
    }
    const short* Bg = Bt + (size_t)(bn0 + srow) * K + scol;
    short* Asb = As + (tid & ~63) * 8;  // wave-uniform LDS base (+lane*16B by HW)
    short* Bsb = Bs + (tid & ~63) * 8;

    for (int k0 = k_start; k0 < k_start + klen; k0 += 64) {
        #pragma unroll
        for (int c = 0; c < 4; c++) {
            gload_lds16(AgC[c] + k0, Asb + c * 2048);
            gload_lds16(Bg + (size_t)(c * 32) * K + k0, Bsb + c * 2048);
        }
        __syncthreads();  // compiler drains vmcnt before barrier
        #pragma unroll
        for (int kk = 0; kk < 2; kk++) {
            short8 af[4], bf[4];
            #pragma unroll
            for (int i = 0; i < 4; i++) {
                af[i] = *reinterpret_cast<const short8*>(&As[(wr * 64 + i * 16 + lrow) * 64 + kk * 32 + lk]);
                bf[i] = *reinterpret_cast<const short8*>(&Bs[(wc * 64 + i * 16 + lrow) * 64 + kk * 32 + lk]);
            }
            #pragma unroll
            for (int mi = 0; mi < 4; mi++)
                #pragma unroll
                for (int ni = 0; ni < 4; ni++)
                    acc[mi][ni] = __builtin_amdgcn_mfma_f32_16x16x32_bf16(bf[ni], af[mi], acc[mi][ni], 0, 0, 0);
        }
        __syncthreads();
    }

    // Swapped-D layout: row = orow0 + mi*16 + (l&15); cols = ocol0 + ni*16 + (l>>4)*4 + reg
    int orow0 = bm0 + wr * 64, ocol0 = bn0 + wc * 64;
    const int lr = l & 15, lq = (l >> 4) * 4;
    #pragma unroll
    for (int mi = 0; mi < 4; mi++) {
        int row = orow0 + mi * 16 + lr;
        float scv = 0.0f;
        int iv = -1;
        if (EPI == 0) scv = sc[GATHER ? sel[row] : row];
        if (EPI == 3) iv = inv[row];
        #pragma unroll
        for (int ni = 0; ni < 4; ni++) {
            int c0 = ocol0 + ni * 16 + lq;
            if (EPI == 0) {
                f32x4 bv = *reinterpret_cast<const f32x4*>(bias + c0);
                u16x4 pk;
                #pragma unroll
                for (int rg = 0; rg < 4; rg++)
                    pk[rg] = f2bf(gelu_fast(fmaf(scv, acc[mi][ni][rg], bv[rg])));
                *reinterpret_cast<u16x4*>((unsigned short*)outb + (size_t)row * N + c0) = pk;
            } else if (EPI == 2) {
                u16x4 pk;
                #pragma unroll
                for (int rg = 0; rg < 4; rg++) pk[rg] = f2bf(acc[mi][ni][rg]);
                *reinterpret_cast<u16x4*>((unsigned short*)outb + ((size_t)bz * M + row) * (size_t)N + c0) = pk;
            } else {  // EPI == 3
                f32x4 bv = *reinterpret_cast<const f32x4*>(bias + c0);
                f32x4 v = acc[mi][ni] + bv;
                if (iv >= 0) {
                    f32x4 hvv = *reinterpret_cast<const f32x4*>(hv + (size_t)iv * DIMD + c0);
                    v = v + hvv;
                }
                *reinterpret_cast<f32x4*>(outf + (size_t)row * N + c0) = v;
            }
        }
    }
}

extern "C" void kernel_launch(void* const* d_in, const int* in_sizes, int n_in,
                              void* d_out, int out_size, void* d_ws, size_t ws_size,
                              hipStream_t stream) {
    (void)in_sizes; (void)n_in; (void)out_size;
    const float* x      = (const float*)d_in[0];
    const float* rt     = (const float*)d_in[1];
    const float* lgamma = (const float*)d_in[2];
    const float* lw1    = (const float*)d_in[3];
    const float* lb1    = (const float*)d_in[4];
    const float* lw2    = (const float*)d_in[5];
    const float* lb2    = (const float*)d_in[6];
    const float* hgamma = (const float*)d_in[7];
    const float* hw1    = (const float*)d_in[8];
    const float* hb1    = (const float*)d_in[9];
    const float* hw2    = (const float*)d_in[10];
    const float* hb2    = (const float*)d_in[11];
    float* out = (float*)d_out;

    auto rnd = [](size_t b) { return (b + 255) & ~(size_t)255; };
    size_t fixed = rnd(NTOK * sizeof(double))        // s
                 + rnd(256)                          // a
                 + rnd(NSEL * sizeof(int))           // sel
                 + rnd(NTOK * sizeof(int))           // inv
                 + rnd(NTOK * sizeof(float))         // sc
                 + rnd((size_t)DLIGHT * DIMD * 2)    // wl1t
                 + rnd((size_t)DIMD * DLIGHT * 2)    // wl2t
                 + rnd((size_t)DHEAVY * DIMD * 2)    // wh1t
                 + rnd((size_t)DIMD * DHEAVY * 2)    // wh2t
                 + rnd((size_t)NTOK * DIMD * 2)      // xb
                 + rnd((size_t)NSEL * DHEAVY * 2)    // hh (aliased by hl)
                 + rnd((size_t)NSEL * DIMD * 4);     // hv (f32)
    int nsk = 4;
    while (nsk > 1 && fixed + rnd((size_t)nsk * NSEL * DIMD * 2) > ws_size) nsk >>= 1;

    char* base = (char*)d_ws;
    size_t off = 0;
    auto alloc = [&](size_t bytes) -> void* {
        void* p = base + off;
        off += rnd(bytes);
        return p;
    };
    double* s     = (double*)alloc(NTOK * sizeof(double));
    double* a_arr = (double*)alloc(256);
    int*    sel   = (int*)alloc(NSEL * sizeof(int));
    int*    inv   = (int*)alloc(NTOK * sizeof(int));
    float*  sc    = (float*)alloc(NTOK * sizeof(float));
    short*  wl1t  = (short*)alloc((size_t)DLIGHT * DIMD * 2);
    short*  wl2t  = (short*)alloc((size_t)DIMD * DLIGHT * 2);
    short*  wh1t  = (short*)alloc((size_t)DHEAVY * DIMD * 2);
    short*  wh2t  = (short*)alloc((size_t)DIMD * DHEAVY * 2);
    short*  xb    = (short*)alloc((size_t)NTOK * DIMD * 2);
    short*  hh    = (short*)alloc((size_t)NSEL * DHEAVY * 2);
    float*  hv    = (float*)alloc((size_t)NSEL * DIMD * 4);
    short*  hl    = hh;  // light GEMM1 output aliases hh (dead after heavy GEMM2)
    short*  phb   = (short*)alloc((size_t)nsk * NSEL * DIMD * 2);

    // weights -> bf16 [N][K]; gamma folded into W1 rows
    cvt_transpose<<<dim3(DLIGHT / 32, DIMD / 32), dim3(32, 8), 0, stream>>>(lw1, (__hip_bfloat16*)wl1t, DIMD, DLIGHT, lgamma);
    cvt_transpose<<<dim3(DIMD / 32, DLIGHT / 32), dim3(32, 8), 0, stream>>>(lw2, (__hip_bfloat16*)wl2t, DLIGHT, DIMD, nullptr);
    cvt_transpose<<<dim3(DHEAVY / 32, DIMD / 32), dim3(32, 8), 0, stream>>>(hw1, (__hip_bfloat16*)wh1t, DIMD, DHEAVY, hgamma);
    cvt_transpose<<<dim3(DIMD / 32, DHEAVY / 32), dim3(32, 8), 0, stream>>>(hw2, (__hip_bfloat16*)wh2t, DHEAVY, DIMD, nullptr);

    hipMemsetAsync(inv, 0xFF, NTOK * sizeof(int), stream);  // inv = -1

    // fused pass: xb=bf16(x), sc, router s
    xpass_kern<<<NTOK, 256, 0, stream>>>(x, rt, (unsigned short*)xb, sc, s);
    descent_kern<<<NBATCH, 1024, 0, stream>>>(s, a_arr);
    select_kern<<<NBATCH, 64, 0, stream>>>(s, a_arr, sel, inv);

    // heavy: GEMM1 (gather rows of xb, sc+gelu epi) -> hh; GEMM2 split-K -> phb; reduce -> hv
    gemm_bt<0, true><<<dim3(DHEAVY / 128, NSEL / 128), 256, 0, stream>>>(
        xb, wh1t, hb1, sc, sel, nullptr, nullptr,
        nullptr, (__hip_bfloat16*)hh, NSEL, DHEAVY, DIMD);
    gemm_bt<2, false><<<dim3(DIMD / 128, NSEL / 128, nsk), 256, 0, stream>>>(
        hh, wh2t, nullptr, nullptr, nullptr, nullptr, nullptr,
        nullptr, (__hip_bfloat16*)phb, NSEL, DIMD, DHEAVY);
    reduce_hv_kern<<<NSEL, 256, 0, stream>>>((const unsigned short*)phb, hb2, hv, nsk);

    // light: GEMM1 -> hl (aliases hh); GEMM2 fused (+hv via inv) -> out
    gemm_bt<0, false><<<dim3(DLIGHT / 128, NTOK / 128), 256, 0, stream>>>(
        xb, wl1t, lb1, sc, nullptr, nullptr, nullptr,
        nullptr, (__hip_bfloat16*)hl, NTOK, DLIGHT, DIMD);
    gemm_bt<3, false><<<dim3(DIMD / 128, NTOK / 128), 256, 0, stream>>>(
        hl, wl2t, lb2, nullptr, nullptr, inv, hv,
        out, nullptr, NTOK, DIMD, DLIGHT);
}

// Round 9
// 459.946 us; speedup vs baseline: 1.2066x; 1.0105x over previous
//
#include <hip/hip_runtime.h>
#include <hip/hip_bf16.h>
#include <math.h>

#define DIMD   1024
#define NBATCH 4
#define NSEQ   8192
#define NTOK   (NBATCH * NSEQ)
#define NHEAVY 1024
#define NSEL   (NBATCH * NHEAVY)
#define DLIGHT 512
#define DHEAVY 4096
#define NITERS 50

typedef __attribute__((ext_vector_type(8))) short short8;
typedef __attribute__((ext_vector_type(4))) float f32x4;
typedef __attribute__((ext_vector_type(4))) unsigned short u16x4;

__device__ __forceinline__ unsigned short f2bf(float f) {
    __hip_bfloat16 h = __float2bfloat16(f);
    union { __hip_bfloat16 h; unsigned short u; } cvt;
    cvt.h = h;
    return cvt.u;
}

__device__ __forceinline__ float bf2f(unsigned short u) {
    return __uint_as_float((unsigned)u << 16);
}

// Abramowitz-Stegun 7.1.26 erf, |eps|<=1.5e-7, single path (no branches).
__device__ __forceinline__ float gelu_fast(float x) {
    float ax = fabsf(x) * 0.7071067811865475f;
    float t = 1.0f / fmaf(0.3275911f, ax, 1.0f);
    float p = fmaf(t, 1.061405429f, -1.453152027f);
    p = fmaf(t, p, 1.421413741f);
    p = fmaf(t, p, -0.284496736f);
    p = fmaf(t, p, 0.254829592f);
    p = p * t;
    float e = __expf(-ax * ax);
    float erf_abs = fmaf(-p, e, 1.0f);
    float erf = copysignf(erf_abs, x);
    return 0.5f * x * (1.0f + erf);
}

__device__ __forceinline__ void gload_lds16(const void* g, void* l) {
    __builtin_amdgcn_global_load_lds(
        (const __attribute__((address_space(1))) void*)g,
        (__attribute__((address_space(3))) void*)l,
        16, 0, 0);
}

// in[K][N] f32 -> out[N][K] bf16, optionally scaling row k by gamma[k].
__global__ void cvt_transpose(const float* __restrict__ in, __hip_bfloat16* __restrict__ out,
                              int K, int N, const float* __restrict__ gamma) {
    __shared__ float tile[32][33];
    int n0 = blockIdx.x * 32, k0 = blockIdx.y * 32;
    int tx = threadIdx.x, ty = threadIdx.y;  // (32, 8)
    #pragma unroll
    for (int j = 0; j < 4; j++) {
        int k = k0 + ty + 8 * j;
        float g = gamma ? gamma[k] : 1.0f;
        tile[ty + 8 * j][tx] = in[(size_t)k * N + (n0 + tx)] * g;
    }
    __syncthreads();
    #pragma unroll
    for (int j = 0; j < 4; j++)
        out[(size_t)(n0 + ty + 8 * j) * K + (k0 + tx)] = __float2bfloat16(tile[tx][ty + 8 * j]);
}

// One block per token: xb = bf16(x_row); sc = 32/max(||x||,1e-12);
// s = dot(x_row, rt) in f64 (same reduction order as prior rounds).
__global__ void xpass_kern(const float* __restrict__ x, const float* __restrict__ rt,
                           unsigned short* __restrict__ xb, float* __restrict__ sc,
                           double* __restrict__ s_out) {
    int t = blockIdx.x;
    int tid = threadIdx.x;  // 256
    const float4* xr = (const float4*)(x + (size_t)t * DIMD);
    float4 v = xr[tid];
    ushort4 pk;
    pk.x = f2bf(v.x); pk.y = f2bf(v.y); pk.z = f2bf(v.z); pk.w = f2bf(v.w);
    ((ushort4*)(xb + (size_t)t * DIMD))[tid] = pk;

    float ss = v.x * v.x + v.y * v.y + v.z * v.z + v.w * v.w;
    float4 rv = ((const float4*)rt)[tid];
    double sd = (double)v.x * rv.x + (double)v.y * rv.y + (double)v.z * rv.z + (double)v.w * rv.w;
    #pragma unroll
    for (int off = 32; off > 0; off >>= 1) {
        ss += __shfl_down(ss, off);
        sd += __shfl_down(sd, off);
    }
    __shared__ float red[4];
    __shared__ double redd[4];
    if ((tid & 63) == 0) { red[tid >> 6] = ss; redd[tid >> 6] = sd; }
    __syncthreads();
    if (tid == 0) {
        s_out[t] = redd[0] + redd[1] + redd[2] + redd[3];
        float tot = red[0] + red[1] + red[2] + red[3];
        sc[t] = 32.0f / fmaxf(sqrtf(tot), 1e-12f);
    }
}

// 50-step coordinate descent per batch row, f64.
__global__ void descent_kern(const double* __restrict__ s, double* __restrict__ a_out) {
    int r = blockIdx.x, tid = threadIdx.x;  // 1024 threads
    const double* sr = s + (size_t)r * NSEQ;
    double es[8];
    #pragma unroll
    for (int i = 0; i < 8; i++) es[i] = exp(sr[tid + i * 1024]);
    __shared__ double red[2][16];
    const double logk = log(1152.0);  // min(1024 * 9/8, 8192)
    double a = logk - log((double)NSEQ);
    for (int it = 1; it < NITERS; it++) {
        double ea = exp(a);
        double loc = 0.0;
        #pragma unroll
        for (int i = 0; i < 8; i++) {
            double p = es[i] * ea;
            loc += (p < 1.0 ? p : 1.0);
        }
        #pragma unroll
        for (int off = 32; off > 0; off >>= 1) loc += __shfl_down(loc, off);
        int pb = it & 1;
        if ((tid & 63) == 0) red[pb][tid >> 6] = loc;
        __syncthreads();
        double S = 0.0;
        #pragma unroll
        for (int i = 0; i < 16; i++) S += red[pb][i];
        a = logk + a - log(S);
    }
    if (tid == 0) a_out[r] = a;
}

// Selection per batch row (1 wave): tokens with s+a>=0 (plateau, lowest-index
// tie-break), fill by descending s. Also writes inv[token] = heavy slot.
__global__ void select_kern(const double* __restrict__ s, const double* __restrict__ a_arr,
                            int* __restrict__ sel, int* __restrict__ inv) {
    int r = blockIdx.x, l = threadIdx.x;  // 64 threads
    const double* sr = s + (size_t)r * NSEQ;
    double a = a_arr[r];
    __shared__ double sw[NSEQ];  // 64 KB
    int cnt = 0;
    for (int base = 0; base < NSEQ; base += 64) {
        int idx = base + l;
        double v = sr[idx];
        bool sat = (v + a) >= 0.0;
        sw[idx] = sat ? -1.0e300 : v;
        unsigned long long m = __ballot(sat);
        int pre = __popcll(m & ((1ull << l) - 1ull));
        if (sat) {
            int slot = cnt + pre;
            if (slot < NHEAVY) {
                sel[r * NHEAVY + slot] = r * NSEQ + idx;
                inv[r * NSEQ + idx] = r * NHEAVY + slot;
            }
        }
        cnt += (int)__popcll(m);
    }
    __syncthreads();
    for (int slot = cnt; slot < NHEAVY; slot++) {  // rarely taken fallback
        double best = -1.0e301; int bidx = NSEQ;
        for (int i = 0; i < NSEQ / 64; i++) {
            int idx = i * 64 + l;
            double v = sw[idx];
            if (v > best) { best = v; bidx = idx; }
        }
        #pragma unroll
        for (int off = 32; off > 0; off >>= 1) {
            double ov = __shfl_down(best, off);
            int oi = __shfl_down(bidx, off);
            if (ov > best || (ov == best && oi < bidx)) { best = ov; bidx = oi; }
        }
        bidx = __shfl(bidx, 0);
        if (l == 0) {
            sel[r * NHEAVY + slot] = r * NSEQ + bidx;
            inv[r * NSEQ + bidx] = r * NHEAVY + slot;
            sw[bidx] = -1.0e300;
        }
        __syncthreads();
    }
}

// hv[h][c] = hb2[c] + sum_j phb[j][h][c]   (dense heavy-output reduce, f32)
__global__ __launch_bounds__(256) void reduce_hv_kern(
    const unsigned short* __restrict__ phb, const float* __restrict__ hb2,
    float* __restrict__ hv, int nsk) {
    int h = blockIdx.x;          // 0..NSEL-1
    int c0 = threadIdx.x * 4;    // 256 threads x 4 cols
    f32x4 acc = *reinterpret_cast<const f32x4*>(hb2 + c0);
    for (int j = 0; j < nsk; j++) {
        u16x4 p = *reinterpret_cast<const u16x4*>(phb + ((size_t)j * NSEL + h) * DIMD + c0);
        #pragma unroll
        for (int rg = 0; rg < 4; rg++) acc[rg] += bf2f(p[rg]);
    }
    *reinterpret_cast<f32x4*>(hv + (size_t)h * DIMD + c0) = acc;
}

// C[M,N] = A[M,K]*Bt[N,K]^T, bf16 in / f32 acc. 128x128 tile, BK=64, 4 waves.
// 2-phase double-buffered K-loop (T3/T4-minimum): stage t+1 before computing t,
// raw s_barrier + counted s_waitcnt vmcnt(8) so next tile's 8 global_load_lds
// stay in flight across the barrier and under the MFMA phase.
// MFMA operand-SWAPPED: mfma(bf, af) -> lane owns row=(l&15)+16*mi, 4 consecutive
// cols (l>>4)*4+reg -> vectorized stores.
// GATHER: A row r comes from A + sel[r]*K (per-lane global src, linear LDS dst).
// EPI 0: bf16 out = gelu(sc_row*acc + bias)      (GEMM1s)
// EPI 2: bf16 partial[bz][m][n] = acc            (heavy GEMM2 split-K, no bias)
// EPI 3: f32 out = acc + bias [+ hv[inv[row]]]   (light GEMM2 fused)
template <int EPI, bool GATHER>
__global__ __launch_bounds__(256) void gemm_bt(
    const short* __restrict__ A, const short* __restrict__ Bt,
    const float* __restrict__ bias,
    const float* __restrict__ sc, const int* __restrict__ sel,
    const int* __restrict__ inv, const float* __restrict__ hv,
    float* __restrict__ outf, __hip_bfloat16* __restrict__ outb,
    int M, int N, int K) {
    __shared__ alignas(16) short As[2][128 * 64];  // 2 x 16 KB
    __shared__ alignas(16) short Bs[2][128 * 64];  // 2 x 16 KB  (total 64 KB)
    // bijective XCD-aware swizzle on the flattened block id (m157/m204)
    int nx = gridDim.x, ny = gridDim.y;
    int nwg = nx * ny * gridDim.z;
    int id = ((int)blockIdx.z * ny + blockIdx.y) * nx + blockIdx.x;
    if ((nwg & 7) == 0) id = (id & 7) * (nwg >> 3) + (id >> 3);
    int bxi = id % nx; int rem = id / nx;
    int byi = rem % ny; int bz = rem / ny;
    int klen = K / (int)gridDim.z, k_start = bz * klen;

    int tid = threadIdx.x;
    int l = tid & 63, w = tid >> 6;
    int wr = w >> 1, wc = w & 1;
    int bn0 = bxi * 128, bm0 = byi * 128;

    f32x4 zero = {0.f, 0.f, 0.f, 0.f};
    f32x4 acc[4][4];
    #pragma unroll
    for (int i = 0; i < 4; i++)
        #pragma unroll
        for (int j = 0; j < 4; j++) acc[i][j] = zero;

    const int lrow = l & 15, lk = (l >> 4) * 8;
    int srow = tid >> 3, scol = (tid & 7) * 8;
    const short* AgC[4];
    const short* BgC[4];
    #pragma unroll
    for (int c = 0; c < 4; c++) {
        int rr = bm0 + srow + c * 32;
        int gr = GATHER ? sel[rr] : rr;
        AgC[c] = A + (size_t)gr * K + scol;
        BgC[c] = Bt + (size_t)(bn0 + srow + c * 32) * K + scol;
    }
    const int sbase = (tid & ~63) * 8;  // wave-uniform LDS base (+lane*16B by HW)

    auto stage = [&](int b, int k0) {
        #pragma unroll
        for (int c = 0; c < 4; c++) {
            gload_lds16(AgC[c] + k0, &As[b][sbase + c * 2048]);
            gload_lds16(BgC[c] + k0, &Bs[b][sbase + c * 2048]);
        }
    };

    int nt = klen / 64;
    stage(0, k_start);
    for (int t = 0; t < nt; ++t) {
        int cur = t & 1;
        if (t + 1 < nt) {
            stage(cur ^ 1, k_start + (t + 1) * 64);
            asm volatile("s_waitcnt vmcnt(8)" ::: "memory");  // cur's stage done; next's 8 in flight
        } else {
            asm volatile("s_waitcnt vmcnt(0)" ::: "memory");
        }
        __builtin_amdgcn_s_barrier();   // raw: no implicit vmcnt(0) drain
        asm volatile("" ::: "memory");  // fence ds_read hoisting above barrier
        #pragma unroll
        for (int kk = 0; kk < 2; kk++) {
            short8 af[4], bf[4];
            #pragma unroll
            for (int i = 0; i < 4; i++) {
                af[i] = *reinterpret_cast<const short8*>(&As[cur][(wr * 64 + i * 16 + lrow) * 64 + kk * 32 + lk]);
                bf[i] = *reinterpret_cast<const short8*>(&Bs[cur][(wc * 64 + i * 16 + lrow) * 64 + kk * 32 + lk]);
            }
            #pragma unroll
            for (int mi = 0; mi < 4; mi++)
                #pragma unroll
                for (int ni = 0; ni < 4; ni++)
                    acc[mi][ni] = __builtin_amdgcn_mfma_f32_16x16x32_bf16(bf[ni], af[mi], acc[mi][ni], 0, 0, 0);
        }
        if (t + 1 < nt) {
            asm volatile("" ::: "memory");  // fence ds_read sinking below barrier
            __builtin_amdgcn_s_barrier();   // all waves done reading buf cur -> t+1 may overwrite
            asm volatile("" ::: "memory");
        }
    }

    // Swapped-D layout: row = orow0 + mi*16 + (l&15); cols = ocol0 + ni*16 + (l>>4)*4 + reg
    int orow0 = bm0 + wr * 64, ocol0 = bn0 + wc * 64;
    const int lr = l & 15, lq = (l >> 4) * 4;
    #pragma unroll
    for (int mi = 0; mi < 4; mi++) {
        int row = orow0 + mi * 16 + lr;
        float scv = 0.0f;
        int iv = -1;
        if (EPI == 0) scv = sc[GATHER ? sel[row] : row];
        if (EPI == 3) iv = inv[row];
        #pragma unroll
        for (int ni = 0; ni < 4; ni++) {
            int c0 = ocol0 + ni * 16 + lq;
            if (EPI == 0) {
                f32x4 bv = *reinterpret_cast<const f32x4*>(bias + c0);
                u16x4 pk;
                #pragma unroll
                for (int rg = 0; rg < 4; rg++)
                    pk[rg] = f2bf(gelu_fast(fmaf(scv, acc[mi][ni][rg], bv[rg])));
                *reinterpret_cast<u16x4*>((unsigned short*)outb + (size_t)row * N + c0) = pk;
            } else if (EPI == 2) {
                u16x4 pk;
                #pragma unroll
                for (int rg = 0; rg < 4; rg++) pk[rg] = f2bf(acc[mi][ni][rg]);
                *reinterpret_cast<u16x4*>((unsigned short*)outb + ((size_t)bz * M + row) * (size_t)N + c0) = pk;
            } else {  // EPI == 3
                f32x4 bv = *reinterpret_cast<const f32x4*>(bias + c0);
                f32x4 v = acc[mi][ni] + bv;
                if (iv >= 0) {
                    f32x4 hvv = *reinterpret_cast<const f32x4*>(hv + (size_t)iv * DIMD + c0);
                    v = v + hvv;
                }
                *reinterpret_cast<f32x4*>(outf + (size_t)row * N + c0) = v;
            }
        }
    }
}

extern "C" void kernel_launch(void* const* d_in, const int* in_sizes, int n_in,
                              void* d_out, int out_size, void* d_ws, size_t ws_size,
                              hipStream_t stream) {
    (void)in_sizes; (void)n_in; (void)out_size;
    const float* x      = (const float*)d_in[0];
    const float* rt     = (const float*)d_in[1];
    const float* lgamma = (const float*)d_in[2];
    const float* lw1    = (const float*)d_in[3];
    const float* lb1    = (const float*)d_in[4];
    const float* lw2    = (const float*)d_in[5];
    const float* lb2    = (const float*)d_in[6];
    const float* hgamma = (const float*)d_in[7];
    const float* hw1    = (const float*)d_in[8];
    const float* hb1    = (const float*)d_in[9];
    const float* hw2    = (const float*)d_in[10];
    const float* hb2    = (const float*)d_in[11];
    float* out = (float*)d_out;

    auto rnd = [](size_t b) { return (b + 255) & ~(size_t)255; };
    size_t fixed = rnd(NTOK * sizeof(double))        // s
                 + rnd(256)                          // a
                 + rnd(NSEL * sizeof(int))           // sel
                 + rnd(NTOK * sizeof(int))           // inv
                 + rnd(NTOK * sizeof(float))         // sc
                 + rnd((size_t)DLIGHT * DIMD * 2)    // wl1t
                 + rnd((size_t)DIMD * DLIGHT * 2)    // wl2t
                 + rnd((size_t)DHEAVY * DIMD * 2)    // wh1t
                 + rnd((size_t)DIMD * DHEAVY * 2)    // wh2t
                 + rnd((size_t)NTOK * DIMD * 2)      // xb
                 + rnd((size_t)NSEL * DHEAVY * 2)    // hh (aliased by hl)
                 + rnd((size_t)NSEL * DIMD * 4);     // hv (f32)
    int nsk = 4;
    while (nsk > 1 && fixed + rnd((size_t)nsk * NSEL * DIMD * 2) > ws_size) nsk >>= 1;

    char* base = (char*)d_ws;
    size_t off = 0;
    auto alloc = [&](size_t bytes) -> void* {
        void* p = base + off;
        off += rnd(bytes);
        return p;
    };
    double* s     = (double*)alloc(NTOK * sizeof(double));
    double* a_arr = (double*)alloc(256);
    int*    sel   = (int*)alloc(NSEL * sizeof(int));
    int*    inv   = (int*)alloc(NTOK * sizeof(int));
    float*  sc    = (float*)alloc(NTOK * sizeof(float));
    short*  wl1t  = (short*)alloc((size_t)DLIGHT * DIMD * 2);
    short*  wl2t  = (short*)alloc((size_t)DIMD * DLIGHT * 2);
    short*  wh1t  = (short*)alloc((size_t)DHEAVY * DIMD * 2);
    short*  wh2t  = (short*)alloc((size_t)DIMD * DHEAVY * 2);
    short*  xb    = (short*)alloc((size_t)NTOK * DIMD * 2);
    short*  hh    = (short*)alloc((size_t)NSEL * DHEAVY * 2);
    float*  hv    = (float*)alloc((size_t)NSEL * DIMD * 4);
    short*  hl    = hh;  // light GEMM1 output aliases hh (dead after heavy GEMM2)
    short*  phb   = (short*)alloc((size_t)nsk * NSEL * DIMD * 2);

    // weights -> bf16 [N][K]; gamma folded into W1 rows
    cvt_transpose<<<dim3(DLIGHT / 32, DIMD / 32), dim3(32, 8), 0, stream>>>(lw1, (__hip_bfloat16*)wl1t, DIMD, DLIGHT, lgamma);
    cvt_transpose<<<dim3(DIMD / 32, DLIGHT / 32), dim3(32, 8), 0, stream>>>(lw2, (__hip_bfloat16*)wl2t, DLIGHT, DIMD, nullptr);
    cvt_transpose<<<dim3(DHEAVY / 32, DIMD / 32), dim3(32, 8), 0, stream>>>(hw1, (__hip_bfloat16*)wh1t, DIMD, DHEAVY, hgamma);
    cvt_transpose<<<dim3(DIMD / 32, DHEAVY / 32), dim3(32, 8), 0, stream>>>(hw2, (__hip_bfloat16*)wh2t, DHEAVY, DIMD, nullptr);

    hipMemsetAsync(inv, 0xFF, NTOK * sizeof(int), stream);  // inv = -1

    // fused pass: xb=bf16(x), sc, router s
    xpass_kern<<<NTOK, 256, 0, stream>>>(x, rt, (unsigned short*)xb, sc, s);
    descent_kern<<<NBATCH, 1024, 0, stream>>>(s, a_arr);
    select_kern<<<NBATCH, 64, 0, stream>>>(s, a_arr, sel, inv);

    // heavy: GEMM1 (gather rows of xb, sc+gelu epi) -> hh; GEMM2 split-K -> phb; reduce -> hv
    gemm_bt<0, true><<<dim3(DHEAVY / 128, NSEL / 128), 256, 0, stream>>>(
        xb, wh1t, hb1, sc, sel, nullptr, nullptr,
        nullptr, (__hip_bfloat16*)hh, NSEL, DHEAVY, DIMD);
    gemm_bt<2, false><<<dim3(DIMD / 128, NSEL / 128, nsk), 256, 0, stream>>>(
        hh, wh2t, nullptr, nullptr, nullptr, nullptr, nullptr,
        nullptr, (__hip_bfloat16*)phb, NSEL, DIMD, DHEAVY);
    reduce_hv_kern<<<NSEL, 256, 0, stream>>>((const unsigned short*)phb, hb2, hv, nsk);

    // light: GEMM1 -> hl (aliases hh); GEMM2 fused (+hv via inv) -> out
    gemm_bt<0, false><<<dim3(DLIGHT / 128, NTOK / 128), 256, 0, stream>>>(
        xb, wl1t, lb1, sc, nullptr, nullptr, nullptr,
        nullptr, (__hip_bfloat16*)hl, NTOK, DLIGHT, DIMD);
    gemm_bt<3, false><<<dim3(DIMD / 128, NTOK / 128), 256, 0, stream>>>(
        hl, wl2t, lb2, nullptr, nullptr, inv, hv,
        out, nullptr, NTOK, DIMD, DLIGHT);
}

// Round 11
// 397.468 us; speedup vs baseline: 1.3963x; 1.1572x over previous
//
#include <hip/hip_runtime.h>
#include <hip/hip_bf16.h>
#include <math.h>

#define DIMD   1024
#define NBATCH 4
#define NSEQ   8192
#define NTOK   (NBATCH * NSEQ)
#define NHEAVY 1024
#define NSEL   (NBATCH * NHEAVY)
#define DLIGHT 512
#define DHEAVY 4096
#define NITERS 50
#define BK     64

typedef __attribute__((ext_vector_type(8))) short short8;
typedef __attribute__((ext_vector_type(4))) float f32x4;
typedef __attribute__((ext_vector_type(4))) unsigned short u16x4;

__device__ __forceinline__ unsigned short f2bf(float f) {
    __hip_bfloat16 h = __float2bfloat16(f);
    union { __hip_bfloat16 h; unsigned short u; } cvt;
    cvt.h = h;
    return cvt.u;
}

__device__ __forceinline__ float bf2f(unsigned short u) {
    return __uint_as_float((unsigned)u << 16);
}

// Abramowitz-Stegun 7.1.26 erf, |eps|<=1.5e-7, single path (no branches).
__device__ __forceinline__ float gelu_fast(float x) {
    float ax = fabsf(x) * 0.7071067811865475f;
    float t = 1.0f / fmaf(0.3275911f, ax, 1.0f);
    float p = fmaf(t, 1.061405429f, -1.453152027f);
    p = fmaf(t, p, 1.421413741f);
    p = fmaf(t, p, -0.284496736f);
    p = fmaf(t, p, 0.254829592f);
    p = p * t;
    float e = __expf(-ax * ax);
    float erf_abs = fmaf(-p, e, 1.0f);
    float erf = copysignf(erf_abs, x);
    return 0.5f * x * (1.0f + erf);
}

__device__ __forceinline__ void gload_lds16(const void* g, void* l) {
    __builtin_amdgcn_global_load_lds(
        (const __attribute__((address_space(1))) void*)g,
        (__attribute__((address_space(3))) void*)l,
        16, 0, 0);
}

// in[K][N] f32 -> out[N][K] bf16, optionally scaling row k by gamma[k].
__global__ void cvt_transpose(const float* __restrict__ in, __hip_bfloat16* __restrict__ out,
                              int K, int N, const float* __restrict__ gamma) {
    __shared__ float tile[32][33];
    int n0 = blockIdx.x * 32, k0 = blockIdx.y * 32;
    int tx = threadIdx.x, ty = threadIdx.y;  // (32, 8)
    #pragma unroll
    for (int j = 0; j < 4; j++) {
        int k = k0 + ty + 8 * j;
        float g = gamma ? gamma[k] : 1.0f;
        tile[ty + 8 * j][tx] = in[(size_t)k * N + (n0 + tx)] * g;
    }
    __syncthreads();
    #pragma unroll
    for (int j = 0; j < 4; j++)
        out[(size_t)(n0 + ty + 8 * j) * K + (k0 + tx)] = __float2bfloat16(tile[tx][ty + 8 * j]);
}

// One block per token: xb = bf16(x_row); sc = 32/max(||x||,1e-12);
// s = dot(x_row, rt) in f64 (same reduction order as prior rounds).
__global__ void xpass_kern(const float* __restrict__ x, const float* __restrict__ rt,
                           unsigned short* __restrict__ xb, float* __restrict__ sc,
                           double* __restrict__ s_out) {
    int t = blockIdx.x;
    int tid = threadIdx.x;  // 256
    const float4* xr = (const float4*)(x + (size_t)t * DIMD);
    float4 v = xr[tid];
    ushort4 pk;
    pk.x = f2bf(v.x); pk.y = f2bf(v.y); pk.z = f2bf(v.z); pk.w = f2bf(v.w);
    ((ushort4*)(xb + (size_t)t * DIMD))[tid] = pk;

    float ss = v.x * v.x + v.y * v.y + v.z * v.z + v.w * v.w;
    float4 rv = ((const float4*)rt)[tid];
    double sd = (double)v.x * rv.x + (double)v.y * rv.y + (double)v.z * rv.z + (double)v.w * rv.w;
    #pragma unroll
    for (int off = 32; off > 0; off >>= 1) {
        ss += __shfl_down(ss, off);
        sd += __shfl_down(sd, off);
    }
    __shared__ float red[4];
    __shared__ double redd[4];
    if ((tid & 63) == 0) { red[tid >> 6] = ss; redd[tid >> 6] = sd; }
    __syncthreads();
    if (tid == 0) {
        s_out[t] = redd[0] + redd[1] + redd[2] + redd[3];
        float tot = red[0] + red[1] + red[2] + red[3];
        sc[t] = 32.0f / fmaxf(sqrtf(tot), 1e-12f);
    }
}

// 50-step coordinate descent per batch row, f64.
__global__ void descent_kern(const double* __restrict__ s, double* __restrict__ a_out) {
    int r = blockIdx.x, tid = threadIdx.x;  // 1024 threads
    const double* sr = s + (size_t)r * NSEQ;
    double es[8];
    #pragma unroll
    for (int i = 0; i < 8; i++) es[i] = exp(sr[tid + i * 1024]);
    __shared__ double red[2][16];
    const double logk = log(1152.0);  // min(1024 * 9/8, 8192)
    double a = logk - log((double)NSEQ);
    for (int it = 1; it < NITERS; it++) {
        double ea = exp(a);
        double loc = 0.0;
        #pragma unroll
        for (int i = 0; i < 8; i++) {
            double p = es[i] * ea;
            loc += (p < 1.0 ? p : 1.0);
        }
        #pragma unroll
        for (int off = 32; off > 0; off >>= 1) loc += __shfl_down(loc, off);
        int pb = it & 1;
        if ((tid & 63) == 0) red[pb][tid >> 6] = loc;
        __syncthreads();
        double S = 0.0;
        #pragma unroll
        for (int i = 0; i < 16; i++) S += red[pb][i];
        a = logk + a - log(S);
    }
    if (tid == 0) a_out[r] = a;
}

// Selection per batch row (1 wave): tokens with s+a>=0 (plateau, lowest-index
// tie-break), fill by descending s. Also writes inv[token] = heavy slot.
__global__ void select_kern(const double* __restrict__ s, const double* __restrict__ a_arr,
                            int* __restrict__ sel, int* __restrict__ inv) {
    int r = blockIdx.x, l = threadIdx.x;  // 64 threads
    const double* sr = s + (size_t)r * NSEQ;
    double a = a_arr[r];
    __shared__ double sw[NSEQ];  // 64 KB
    int cnt = 0;
    for (int base = 0; base < NSEQ; base += 64) {
        int idx = base + l;
        double v = sr[idx];
        bool sat = (v + a) >= 0.0;
        sw[idx] = sat ? -1.0e300 : v;
        unsigned long long m = __ballot(sat);
        int pre = __popcll(m & ((1ull << l) - 1ull));
        if (sat) {
            int slot = cnt + pre;
            if (slot < NHEAVY) {
                sel[r * NHEAVY + slot] = r * NSEQ + idx;
                inv[r * NSEQ + idx] = r * NHEAVY + slot;
            }
        }
        cnt += (int)__popcll(m);
    }
    __syncthreads();
    for (int slot = cnt; slot < NHEAVY; slot++) {  // rarely taken fallback
        double best = -1.0e301; int bidx = NSEQ;
        for (int i = 0; i < NSEQ / 64; i++) {
            int idx = i * 64 + l;
            double v = sw[idx];
            if (v > best) { best = v; bidx = idx; }
        }
        #pragma unroll
        for (int off = 32; off > 0; off >>= 1) {
            double ov = __shfl_down(best, off);
            int oi = __shfl_down(bidx, off);
            if (ov > best || (ov == best && oi < bidx)) { best = ov; bidx = oi; }
        }
        bidx = __shfl(bidx, 0);
        if (l == 0) {
            sel[r * NHEAVY + slot] = r * NSEQ + bidx;
            inv[r * NSEQ + bidx] = r * NHEAVY + slot;
            sw[bidx] = -1.0e300;
        }
        __syncthreads();
    }
}

// hv[h][c] = hb2[c] + sum_j phb[j][h][c]   (dense heavy-output reduce, f32)
__global__ __launch_bounds__(256) void reduce_hv_kern(
    const unsigned short* __restrict__ phb, const float* __restrict__ hb2,
    float* __restrict__ hv, int nsk) {
    int h = blockIdx.x;          // 0..NSEL-1
    int c0 = threadIdx.x * 4;    // 256 threads x 4 cols
    f32x4 acc = *reinterpret_cast<const f32x4*>(hb2 + c0);
    for (int j = 0; j < nsk; j++) {
        u16x4 p = *reinterpret_cast<const u16x4*>(phb + ((size_t)j * NSEL + h) * DIMD + c0);
        #pragma unroll
        for (int rg = 0; rg < 4; rg++) acc[rg] += bf2f(p[rg]);
    }
    *reinterpret_cast<f32x4*>(hv + (size_t)h * DIMD + c0) = acc;
}

// ===== 256x256 8-phase GEMM (T2 swizzle + T3/T4 counted vmcnt + T5 setprio) =====
// C[M,N] = A[M,K]*Bt[N,K]^T, bf16 in / f32 acc. 8 waves (2M x 4N), per-wave 128x64.
// LDS: 2 dbuf x 2 halves x [128][64] bf16 for A and B = 128 KB.
// T2: st-swizzle byte^=((row&7)<<4), applied via pre-swizzled GLOBAL source
// (linear gload_lds dest) + swizzled ds_read addresses. NOTE: the read-side
// column must include the kk*64 term INSIDE the XOR (bit 6 participates);
// adding kk*64 after the XOR carries into the row bits for rows 4-7 mod 8
// (round-10 correctness bug).
// Schedule per K-tile t (4 quadrant phases): ds-read subtile; stage 1 half-tile
// (A(t+1) in phases 0-1 -> other buffer; B(t+2) in phases 2-3 -> same buffer,
// safe: B fully consumed in phase 0, two barriers earlier); phase 3: counted
// vmcnt(4) (=B(t+2)'s 4 loads outstanding) -> next tile landed; barrier;
// setprio(1) 16 MFMA setprio(0); barrier.
// MFMA operand-swapped: mfma(bf, af) -> lane owns row=(l&15), 4 consecutive cols.
// EPI 0: bf16 out = gelu(sc_row*acc + bias)      (GEMM1s; sc via sel if GATHER)
// EPI 2: bf16 partial[bz][m][n] = acc            (heavy GEMM2 split-K)
// EPI 3: f32 out = acc + bias [+ hv[inv[row]]]   (light GEMM2 fused)
template <int EPI, bool GATHER>
__global__ __launch_bounds__(512, 2) void gemm256(
    const short* __restrict__ A, const short* __restrict__ Bt,
    const float* __restrict__ bias,
    const float* __restrict__ sc, const int* __restrict__ sel,
    const int* __restrict__ inv, const float* __restrict__ hv,
    float* __restrict__ outf, __hip_bfloat16* __restrict__ outb,
    int M, int N, int K) {
    __shared__ alignas(16) short As[2][2][128 * 64];  // [dbuf][half] 16 KB each
    __shared__ alignas(16) short Bs[2][2][128 * 64];

    // bijective XCD-aware swizzle on the flattened block id
    int nx = gridDim.x, ny = gridDim.y;
    int nwg = nx * ny * gridDim.z;
    int id = ((int)blockIdx.z * ny + blockIdx.y) * nx + blockIdx.x;
    if ((nwg & 7) == 0) id = (id & 7) * (nwg >> 3) + (id >> 3);
    int bxi = id % nx; int rem = id / nx;
    int byi = rem % ny; int bz = rem / ny;
    int klen = K / (int)gridDim.z, k0base = bz * klen;
    int bn0 = bxi * 256, bm0 = byi * 256;

    int tid = threadIdx.x;
    int l = tid & 63, w = tid >> 6;   // 8 waves
    int wr = w >> 2, wc = w & 3;      // 2 x 4

    f32x4 zero = {0.f, 0.f, 0.f, 0.f};
    f32x4 acc[8][4];
    #pragma unroll
    for (int i = 0; i < 8; i++)
        #pragma unroll
        for (int j = 0; j < 4; j++) acc[i][j] = zero;

    // staging source pointers: per (half h, issue j) thread covers LDS bytes
    // p = j*8192 + tid*16 of a [128][64]-bf16 half; fetch global at swizzled
    // offset o = p ^ ((p>>7 & 7) << 4)  (involution, 16B-chunk preserving).
    const short* aSrc[2][2];
    const short* bSrc[2][2];
    #pragma unroll
    for (int h = 0; h < 2; h++)
        #pragma unroll
        for (int j = 0; j < 2; j++) {
            int p = j * 8192 + tid * 16;
            int o = p ^ (((p >> 7) & 7) << 4);
            int lrow = o >> 7, colb = o & 127;
            int agrow = bm0 + h * 128 + lrow;
            int garow = GATHER ? sel[agrow] : agrow;
            aSrc[h][j] = A + (size_t)garow * K + (colb >> 1);
            bSrc[h][j] = Bt + (size_t)(bn0 + h * 128 + lrow) * K + (colb >> 1);
        }

    auto stageA = [&](int b, int h, int kof) {
        #pragma unroll
        for (int j = 0; j < 2; j++)
            gload_lds16(aSrc[h][j] + kof, &As[b][h][j * 4096 + w * 512]);
    };
    auto stageB = [&](int b, int h, int kof) {
        #pragma unroll
        for (int j = 0; j < 2; j++)
            gload_lds16(bSrc[h][j] + kof, &Bs[b][h][j * 4096 + w * 512]);
    };

    int nt = klen / BK;
    // prologue: A(0), B(0), B(1)
    stageA(0, 0, k0base); stageA(0, 1, k0base);
    stageB(0, 0, k0base); stageB(0, 1, k0base);
    if (nt > 1) {
        stageB(1, 0, k0base + BK); stageB(1, 1, k0base + BK);
        asm volatile("s_waitcnt vmcnt(4)" ::: "memory");
    } else {
        asm volatile("s_waitcnt vmcnt(0)" ::: "memory");
    }
    __builtin_amdgcn_s_barrier();
    asm volatile("" ::: "memory");

    // swizzled ds_read columns: actual row within half has row&7 == lr&7 for
    // all fragment rows (subtile strides are multiples of 8 rows), so
    // col_kk = ((l>>4)*16 + kk*64) ^ ((lr&7)<<4), addr = row*128 + col_kk.
    const int lr = l & 15;
    const int swz = (lr & 7) << 4;
    const int rbase = lr * 128;
    const int colk[2] = { (((l >> 4) * 16)) ^ swz, (((l >> 4) * 16) + 64) ^ swz };

    short8 bfr[4][2];
    for (int t = 0; t < nt; ++t) {
        int d = t & 1;
        const char* aHalf = (const char*)(&As[d][wr][0]);
        const char* bHalf = (const char*)(&Bs[d][wc >> 1][0]) + (wc & 1) * 8192;
        #pragma unroll
        for (int q = 0; q < 4; q++) {
            if (q == 0) {
                #pragma unroll
                for (int ni = 0; ni < 4; ni++)
                    #pragma unroll
                    for (int kk = 0; kk < 2; kk++)
                        bfr[ni][kk] = *reinterpret_cast<const short8*>(bHalf + rbase + ni * 2048 + colk[kk]);
            }
            short8 afr[2][2];
            #pragma unroll
            for (int m2 = 0; m2 < 2; m2++)
                #pragma unroll
                for (int kk = 0; kk < 2; kk++)
                    afr[m2][kk] = *reinterpret_cast<const short8*>(aHalf + rbase + (q * 2 + m2) * 2048 + colk[kk]);
            if (q == 0 && t + 1 < nt) stageA(d ^ 1, 0, k0base + (t + 1) * BK);
            else if (q == 1 && t + 1 < nt) stageA(d ^ 1, 1, k0base + (t + 1) * BK);
            else if (q == 2 && t + 2 < nt) stageB(d, 0, k0base + (t + 2) * BK);
            else if (q == 3 && t + 2 < nt) stageB(d, 1, k0base + (t + 2) * BK);
            if (q == 3) {
                if (t + 2 < nt) asm volatile("s_waitcnt vmcnt(4)" ::: "memory");
                else if (t + 1 < nt) asm volatile("s_waitcnt vmcnt(0)" ::: "memory");
                else asm volatile("s_waitcnt vmcnt(0)" ::: "memory");
            }
            asm volatile("" ::: "memory");
            __builtin_amdgcn_s_barrier();
            asm volatile("" ::: "memory");
            __builtin_amdgcn_s_setprio(1);
            #pragma unroll
            for (int m2 = 0; m2 < 2; m2++)
                #pragma unroll
                for (int ni = 0; ni < 4; ni++)
                    #pragma unroll
                    for (int kk = 0; kk < 2; kk++)
                        acc[q * 2 + m2][ni] = __builtin_amdgcn_mfma_f32_16x16x32_bf16(
                            bfr[ni][kk], afr[m2][kk], acc[q * 2 + m2][ni], 0, 0, 0);
            __builtin_amdgcn_s_setprio(0);
            asm volatile("" ::: "memory");
            __builtin_amdgcn_s_barrier();
            asm volatile("" ::: "memory");
        }
    }

    // Swapped-D: row = bm0 + wr*128 + mi*16 + (l&15); cols = bn0 + wc*64 + ni*16 + (l>>4)*4 + reg
    int orow0 = bm0 + wr * 128, ocol0 = bn0 + wc * 64;
    const int lq = (l >> 4) * 4;
    #pragma unroll
    for (int mi = 0; mi < 8; mi++) {
        int row = orow0 + mi * 16 + lr;
        float scv = 0.0f;
        int iv = -1;
        if (EPI == 0) scv = sc[GATHER ? sel[row] : row];
        if (EPI == 3) iv = inv[row];
        #pragma unroll
        for (int ni = 0; ni < 4; ni++) {
            int c0 = ocol0 + ni * 16 + lq;
            if (EPI == 0) {
                f32x4 bv = *reinterpret_cast<const f32x4*>(bias + c0);
                u16x4 pk;
                #pragma unroll
                for (int rg = 0; rg < 4; rg++)
                    pk[rg] = f2bf(gelu_fast(fmaf(scv, acc[mi][ni][rg], bv[rg])));
                *reinterpret_cast<u16x4*>((unsigned short*)outb + (size_t)row * N + c0) = pk;
            } else if (EPI == 2) {
                u16x4 pk;
                #pragma unroll
                for (int rg = 0; rg < 4; rg++) pk[rg] = f2bf(acc[mi][ni][rg]);
                *reinterpret_cast<u16x4*>((unsigned short*)outb + ((size_t)bz * M + row) * (size_t)N + c0) = pk;
            } else {  // EPI == 3
                f32x4 bv = *reinterpret_cast<const f32x4*>(bias + c0);
                f32x4 v = acc[mi][ni] + bv;
                if (iv >= 0) {
                    f32x4 hvv = *reinterpret_cast<const f32x4*>(hv + (size_t)iv * DIMD + c0);
                    v = v + hvv;
                }
                *reinterpret_cast<f32x4*>(outf + (size_t)row * N + c0) = v;
            }
        }
    }
}

extern "C" void kernel_launch(void* const* d_in, const int* in_sizes, int n_in,
                              void* d_out, int out_size, void* d_ws, size_t ws_size,
                              hipStream_t stream) {
    (void)in_sizes; (void)n_in; (void)out_size;
    const float* x      = (const float*)d_in[0];
    const float* rt     = (const float*)d_in[1];
    const float* lgamma = (const float*)d_in[2];
    const float* lw1    = (const float*)d_in[3];
    const float* lb1    = (const float*)d_in[4];
    const float* lw2    = (const float*)d_in[5];
    const float* lb2    = (const float*)d_in[6];
    const float* hgamma = (const float*)d_in[7];
    const float* hw1    = (const float*)d_in[8];
    const float* hb1    = (const float*)d_in[9];
    const float* hw2    = (const float*)d_in[10];
    const float* hb2    = (const float*)d_in[11];
    float* out = (float*)d_out;

    auto rnd = [](size_t b) { return (b + 255) & ~(size_t)255; };
    size_t fixed = rnd(NTOK * sizeof(double))        // s
                 + rnd(256)                          // a
                 + rnd(NSEL * sizeof(int))           // sel
                 + rnd(NTOK * sizeof(int))           // inv
                 + rnd(NTOK * sizeof(float))         // sc
                 + rnd((size_t)DLIGHT * DIMD * 2)    // wl1t
                 + rnd((size_t)DIMD * DLIGHT * 2)    // wl2t
                 + rnd((size_t)DHEAVY * DIMD * 2)    // wh1t
                 + rnd((size_t)DIMD * DHEAVY * 2)    // wh2t
                 + rnd((size_t)NTOK * DIMD * 2)      // xb
                 + rnd((size_t)NSEL * DHEAVY * 2)    // hh (aliased by hl)
                 + rnd((size_t)NSEL * DIMD * 4);     // hv (f32)
    int nsk = 4;
    while (nsk > 1 && fixed + rnd((size_t)nsk * NSEL * DIMD * 2) > ws_size) nsk >>= 1;

    char* base = (char*)d_ws;
    size_t off = 0;
    auto alloc = [&](size_t bytes) -> void* {
        void* p = base + off;
        off += rnd(bytes);
        return p;
    };
    double* s     = (double*)alloc(NTOK * sizeof(double));
    double* a_arr = (double*)alloc(256);
    int*    sel   = (int*)alloc(NSEL * sizeof(int));
    int*    inv   = (int*)alloc(NTOK * sizeof(int));
    float*  sc    = (float*)alloc(NTOK * sizeof(float));
    short*  wl1t  = (short*)alloc((size_t)DLIGHT * DIMD * 2);
    short*  wl2t  = (short*)alloc((size_t)DIMD * DLIGHT * 2);
    short*  wh1t  = (short*)alloc((size_t)DHEAVY * DIMD * 2);
    short*  wh2t  = (short*)alloc((size_t)DIMD * DHEAVY * 2);
    short*  xb    = (short*)alloc((size_t)NTOK * DIMD * 2);
    short*  hh    = (short*)alloc((size_t)NSEL * DHEAVY * 2);
    float*  hv    = (float*)alloc((size_t)NSEL * DIMD * 4);
    short*  hl    = hh;  // light GEMM1 output aliases hh (dead after heavy GEMM2)
    short*  phb   = (short*)alloc((size_t)nsk * NSEL * DIMD * 2);

    // weights -> bf16 [N][K]; gamma folded into W1 rows
    cvt_transpose<<<dim3(DLIGHT / 32, DIMD / 32), dim3(32, 8), 0, stream>>>(lw1, (__hip_bfloat16*)wl1t, DIMD, DLIGHT, lgamma);
    cvt_transpose<<<dim3(DIMD / 32, DLIGHT / 32), dim3(32, 8), 0, stream>>>(lw2, (__hip_bfloat16*)wl2t, DLIGHT, DIMD, nullptr);
    cvt_transpose<<<dim3(DHEAVY / 32, DIMD / 32), dim3(32, 8), 0, stream>>>(hw1, (__hip_bfloat16*)wh1t, DIMD, DHEAVY, hgamma);
    cvt_transpose<<<dim3(DIMD / 32, DHEAVY / 32), dim3(32, 8), 0, stream>>>(hw2, (__hip_bfloat16*)wh2t, DHEAVY, DIMD, nullptr);

    hipMemsetAsync(inv, 0xFF, NTOK * sizeof(int), stream);  // inv = -1

    // fused pass: xb=bf16(x), sc, router s
    xpass_kern<<<NTOK, 256, 0, stream>>>(x, rt, (unsigned short*)xb, sc, s);
    descent_kern<<<NBATCH, 1024, 0, stream>>>(s, a_arr);
    select_kern<<<NBATCH, 64, 0, stream>>>(s, a_arr, sel, inv);

    // heavy: GEMM1 (gather rows of xb, sc+gelu epi) -> hh; GEMM2 split-K -> phb; reduce -> hv
    gemm256<0, true><<<dim3(DHEAVY / 256, NSEL / 256), 512, 0, stream>>>(
        xb, wh1t, hb1, sc, sel, nullptr, nullptr,
        nullptr, (__hip_bfloat16*)hh, NSEL, DHEAVY, DIMD);
    gemm256<2, false><<<dim3(DIMD / 256, NSEL / 256, nsk), 512, 0, stream>>>(
        hh, wh2t, nullptr, nullptr, nullptr, nullptr, nullptr,
        nullptr, (__hip_bfloat16*)phb, NSEL, DIMD, DHEAVY);
    reduce_hv_kern<<<NSEL, 256, 0, stream>>>((const unsigned short*)phb, hb2, hv, nsk);

    // light: GEMM1 -> hl (aliases hh); GEMM2 fused (+hv via inv) -> out
    gemm256<0, false><<<dim3(DLIGHT / 256, NTOK / 256), 512, 0, stream>>>(
        xb, wl1t, lb1, sc, nullptr, nullptr, nullptr,
        nullptr, (__hip_bfloat16*)hl, NTOK, DLIGHT, DIMD);
    gemm256<3, false><<<dim3(DIMD / 256, NTOK / 256), 512, 0, stream>>>(
        hl, wl2t, lb2, nullptr, nullptr, inv, hv,
        out, nullptr, NTOK, DIMD, DLIGHT);
}

// Round 12
// 389.249 us; speedup vs baseline: 1.4258x; 1.0211x over previous
//
#include <hip/hip_runtime.h>
#include <hip/hip_bf16.h>
#include <math.h>

#define DIMD   1024
#define NBATCH 4
#define NSEQ   8192
#define NTOK   (NBATCH * NSEQ)
#define NHEAVY 1024
#define NSEL   (NBATCH * NHEAVY)
#define DLIGHT 512
#define DHEAVY 4096
#define NITERS 50
#define BK     64

typedef __attribute__((ext_vector_type(8))) short short8;
typedef __attribute__((ext_vector_type(4))) float f32x4;
typedef __attribute__((ext_vector_type(4))) unsigned short u16x4;

__device__ __forceinline__ unsigned short f2bf(float f) {
    __hip_bfloat16 h = __float2bfloat16(f);
    union { __hip_bfloat16 h; unsigned short u; } cvt;
    cvt.h = h;
    return cvt.u;
}

__device__ __forceinline__ float bf2f(unsigned short u) {
    return __uint_as_float((unsigned)u << 16);
}

// Abramowitz-Stegun 7.1.26 erf, |eps|<=1.5e-7, single path (no branches).
__device__ __forceinline__ float gelu_fast(float x) {
    float ax = fabsf(x) * 0.7071067811865475f;
    float t = 1.0f / fmaf(0.3275911f, ax, 1.0f);
    float p = fmaf(t, 1.061405429f, -1.453152027f);
    p = fmaf(t, p, 1.421413741f);
    p = fmaf(t, p, -0.284496736f);
    p = fmaf(t, p, 0.254829592f);
    p = p * t;
    float e = __expf(-ax * ax);
    float erf_abs = fmaf(-p, e, 1.0f);
    float erf = copysignf(erf_abs, x);
    return 0.5f * x * (1.0f + erf);
}

__device__ __forceinline__ void gload_lds16(const void* g, void* l) {
    __builtin_amdgcn_global_load_lds(
        (const __attribute__((address_space(1))) void*)g,
        (__attribute__((address_space(3))) void*)l,
        16, 0, 0);
}

// in[K][N] f32 -> out[N][K] bf16, optionally scaling row k by gamma[k].
__global__ void cvt_transpose(const float* __restrict__ in, __hip_bfloat16* __restrict__ out,
                              int K, int N, const float* __restrict__ gamma) {
    __shared__ float tile[32][33];
    int n0 = blockIdx.x * 32, k0 = blockIdx.y * 32;
    int tx = threadIdx.x, ty = threadIdx.y;  // (32, 8)
    #pragma unroll
    for (int j = 0; j < 4; j++) {
        int k = k0 + ty + 8 * j;
        float g = gamma ? gamma[k] : 1.0f;
        tile[ty + 8 * j][tx] = in[(size_t)k * N + (n0 + tx)] * g;
    }
    __syncthreads();
    #pragma unroll
    for (int j = 0; j < 4; j++)
        out[(size_t)(n0 + ty + 8 * j) * K + (k0 + tx)] = __float2bfloat16(tile[tx][ty + 8 * j]);
}

// One block per token: xb = bf16(x_row); sc = 32/max(||x||,1e-12);
// s = dot(x_row, rt) in f64 (same reduction order as prior rounds).
__global__ void xpass_kern(const float* __restrict__ x, const float* __restrict__ rt,
                           unsigned short* __restrict__ xb, float* __restrict__ sc,
                           double* __restrict__ s_out) {
    int t = blockIdx.x;
    int tid = threadIdx.x;  // 256
    const float4* xr = (const float4*)(x + (size_t)t * DIMD);
    float4 v = xr[tid];
    ushort4 pk;
    pk.x = f2bf(v.x); pk.y = f2bf(v.y); pk.z = f2bf(v.z); pk.w = f2bf(v.w);
    ((ushort4*)(xb + (size_t)t * DIMD))[tid] = pk;

    float ss = v.x * v.x + v.y * v.y + v.z * v.z + v.w * v.w;
    float4 rv = ((const float4*)rt)[tid];
    double sd = (double)v.x * rv.x + (double)v.y * rv.y + (double)v.z * rv.z + (double)v.w * rv.w;
    #pragma unroll
    for (int off = 32; off > 0; off >>= 1) {
        ss += __shfl_down(ss, off);
        sd += __shfl_down(sd, off);
    }
    __shared__ float red[4];
    __shared__ double redd[4];
    if ((tid & 63) == 0) { red[tid >> 6] = ss; redd[tid >> 6] = sd; }
    __syncthreads();
    if (tid == 0) {
        s_out[t] = redd[0] + redd[1] + redd[2] + redd[3];
        float tot = red[0] + red[1] + red[2] + red[3];
        sc[t] = 32.0f / fmaxf(sqrtf(tot), 1e-12f);
    }
}

// 50-step coordinate descent per batch row, f64, exp-domain (multiplicative).
// a <- logk + a - log(S)  ==  ea <- ea * (K/S), with S = sum_i min(es_i*ea, 1).
// No per-iteration transcendentals (was exp(a)+log(S) ~= 2 x ~1k cyc serial);
// a = log(ea) computed once at the end. Reduction tree order unchanged.
__global__ void descent_kern(const double* __restrict__ s, double* __restrict__ a_out) {
    int r = blockIdx.x, tid = threadIdx.x;  // 1024 threads
    const double* sr = s + (size_t)r * NSEQ;
    double es[8];
    #pragma unroll
    for (int i = 0; i < 8; i++) es[i] = exp(sr[tid + i * 1024]);
    __shared__ double red[2][16];
    const double Kk = 1152.0;  // min(1024 * 9/8, 8192)
    double ea = exp(log(Kk) - log((double)NSEQ));  // e^{a_1}
    for (int it = 1; it < NITERS; it++) {
        double loc = 0.0;
        #pragma unroll
        for (int i = 0; i < 8; i++) {
            double p = es[i] * ea;
            loc += (p < 1.0 ? p : 1.0);
        }
        #pragma unroll
        for (int off = 32; off > 0; off >>= 1) loc += __shfl_down(loc, off);
        int pb = it & 1;
        if ((tid & 63) == 0) red[pb][tid >> 6] = loc;
        __syncthreads();
        double S = 0.0;
        #pragma unroll
        for (int i = 0; i < 16; i++) S += red[pb][i];
        ea = ea * (Kk / S);  // redundant per-thread; deterministic, saves a 2nd barrier
    }
    if (tid == 0) a_out[r] = log(ea);
}

// Selection per batch row (1 wave): tokens with s+a>=0 (plateau, lowest-index
// tie-break), fill by descending s. Also writes inv[token] = heavy slot.
__global__ void select_kern(const double* __restrict__ s, const double* __restrict__ a_arr,
                            int* __restrict__ sel, int* __restrict__ inv) {
    int r = blockIdx.x, l = threadIdx.x;  // 64 threads
    const double* sr = s + (size_t)r * NSEQ;
    double a = a_arr[r];
    __shared__ double sw[NSEQ];  // 64 KB
    int cnt = 0;
    for (int base = 0; base < NSEQ; base += 64) {
        int idx = base + l;
        double v = sr[idx];
        bool sat = (v + a) >= 0.0;
        sw[idx] = sat ? -1.0e300 : v;
        unsigned long long m = __ballot(sat);
        int pre = __popcll(m & ((1ull << l) - 1ull));
        if (sat) {
            int slot = cnt + pre;
            if (slot < NHEAVY) {
                sel[r * NHEAVY + slot] = r * NSEQ + idx;
                inv[r * NSEQ + idx] = r * NHEAVY + slot;
            }
        }
        cnt += (int)__popcll(m);
    }
    __syncthreads();
    for (int slot = cnt; slot < NHEAVY; slot++) {  // rarely taken fallback
        double best = -1.0e301; int bidx = NSEQ;
        for (int i = 0; i < NSEQ / 64; i++) {
            int idx = i * 64 + l;
            double v = sw[idx];
            if (v > best) { best = v; bidx = idx; }
        }
        #pragma unroll
        for (int off = 32; off > 0; off >>= 1) {
            double ov = __shfl_down(best, off);
            int oi = __shfl_down(bidx, off);
            if (ov > best || (ov == best && oi < bidx)) { best = ov; bidx = oi; }
        }
        bidx = __shfl(bidx, 0);
        if (l == 0) {
            sel[r * NHEAVY + slot] = r * NSEQ + bidx;
            inv[r * NSEQ + bidx] = r * NHEAVY + slot;
            sw[bidx] = -1.0e300;
        }
        __syncthreads();
    }
}

// ===== 256x256 8-phase GEMM (T2 swizzle + T3/T4 counted vmcnt + T5 setprio) =====
// C[M,N] = A[M,K]*Bt[N,K]^T, bf16 in / f32 acc. 8 waves (2M x 4N), per-wave 128x64.
// LDS: 2 dbuf x 2 halves x [128][64] bf16 for A and B = 128 KB.
// T2: st-swizzle byte^=((row&7)<<4) via pre-swizzled GLOBAL source (linear
// gload_lds dest) + swizzled ds_read addresses; kk*64 must be XORed INSIDE
// the column (bit 6 participates in the swizzle) — round-10 lesson.
// Schedule per K-tile t (4 quadrant phases): ds-read subtile; stage 1 half-tile
// (A(t+1) in phases 0-1 -> other buffer; B(t+2) in phases 2-3 -> same buffer,
// safe: B fully consumed in phase 0, two barriers earlier); phase 3: counted
// vmcnt(4) -> next tile landed; barrier; setprio(1) 16 MFMA setprio(0); barrier.
// MFMA operand-swapped: mfma(bf, af) -> lane owns row=(l&15), 4 consecutive cols.
// EPI 0: bf16 out = gelu(sc_row*acc + bias)      (GEMM1s; sc via sel if GATHER)
// EPI 2: bf16 partial[bz][m][n] = acc            (heavy GEMM2 split-K)
// EPI 3: f32 out = acc + bias [+ bias2 + sum_j phb[j][inv[row]]]  (light GEMM2,
//        heavy partials folded in-place — reduce_hv kernel deleted)
template <int EPI, bool GATHER>
__global__ __launch_bounds__(512, 2) void gemm256(
    const short* __restrict__ A, const short* __restrict__ Bt,
    const float* __restrict__ bias, const float* __restrict__ bias2,
    const float* __restrict__ sc, const int* __restrict__ sel,
    const int* __restrict__ inv, const unsigned short* __restrict__ phb, int nsk,
    float* __restrict__ outf, __hip_bfloat16* __restrict__ outb,
    int M, int N, int K) {
    __shared__ alignas(16) short As[2][2][128 * 64];  // [dbuf][half] 16 KB each
    __shared__ alignas(16) short Bs[2][2][128 * 64];

    // bijective XCD-aware swizzle on the flattened block id
    int nx = gridDim.x, ny = gridDim.y;
    int nwg = nx * ny * gridDim.z;
    int id = ((int)blockIdx.z * ny + blockIdx.y) * nx + blockIdx.x;
    if ((nwg & 7) == 0) id = (id & 7) * (nwg >> 3) + (id >> 3);
    int bxi = id % nx; int rem = id / nx;
    int byi = rem % ny; int bz = rem / ny;
    int klen = K / (int)gridDim.z, k0base = bz * klen;
    int bn0 = bxi * 256, bm0 = byi * 256;

    int tid = threadIdx.x;
    int l = tid & 63, w = tid >> 6;   // 8 waves
    int wr = w >> 2, wc = w & 3;      // 2 x 4

    f32x4 zero = {0.f, 0.f, 0.f, 0.f};
    f32x4 acc[8][4];
    #pragma unroll
    for (int i = 0; i < 8; i++)
        #pragma unroll
        for (int j = 0; j < 4; j++) acc[i][j] = zero;

    // staging source pointers: per (half h, issue j) thread covers LDS bytes
    // p = j*8192 + tid*16 of a [128][64]-bf16 half; fetch global at swizzled
    // offset o = p ^ ((p>>7 & 7) << 4)  (involution, 16B-chunk preserving).
    const short* aSrc[2][2];
    const short* bSrc[2][2];
    #pragma unroll
    for (int h = 0; h < 2; h++)
        #pragma unroll
        for (int j = 0; j < 2; j++) {
            int p = j * 8192 + tid * 16;
            int o = p ^ (((p >> 7) & 7) << 4);
            int lrow = o >> 7, colb = o & 127;
            int agrow = bm0 + h * 128 + lrow;
            int garow = GATHER ? sel[agrow] : agrow;
            aSrc[h][j] = A + (size_t)garow * K + (colb >> 1);
            bSrc[h][j] = Bt + (size_t)(bn0 + h * 128 + lrow) * K + (colb >> 1);
        }

    auto stageA = [&](int b, int h, int kof) {
        #pragma unroll
        for (int j = 0; j < 2; j++)
            gload_lds16(aSrc[h][j] + kof, &As[b][h][j * 4096 + w * 512]);
    };
    auto stageB = [&](int b, int h, int kof) {
        #pragma unroll
        for (int j = 0; j < 2; j++)
            gload_lds16(bSrc[h][j] + kof, &Bs[b][h][j * 4096 + w * 512]);
    };

    int nt = klen / BK;
    // prologue: A(0), B(0), B(1)
    stageA(0, 0, k0base); stageA(0, 1, k0base);
    stageB(0, 0, k0base); stageB(0, 1, k0base);
    if (nt > 1) {
        stageB(1, 0, k0base + BK); stageB(1, 1, k0base + BK);
        asm volatile("s_waitcnt vmcnt(4)" ::: "memory");
    } else {
        asm volatile("s_waitcnt vmcnt(0)" ::: "memory");
    }
    __builtin_amdgcn_s_barrier();
    asm volatile("" ::: "memory");

    // swizzled ds_read columns: row&7 == lr&7 for all fragment rows (subtile
    // strides are multiples of 8 rows): col_kk = ((l>>4)*16 + kk*64) ^ swz.
    const int lr = l & 15;
    const int swz = (lr & 7) << 4;
    const int rbase = lr * 128;
    const int colk[2] = { (((l >> 4) * 16)) ^ swz, (((l >> 4) * 16) + 64) ^ swz };

    short8 bfr[4][2];
    for (int t = 0; t < nt; ++t) {
        int d = t & 1;
        const char* aHalf = (const char*)(&As[d][wr][0]);
        const char* bHalf = (const char*)(&Bs[d][wc >> 1][0]) + (wc & 1) * 8192;
        #pragma unroll
        for (int q = 0; q < 4; q++) {
            if (q == 0) {
                #pragma unroll
                for (int ni = 0; ni < 4; ni++)
                    #pragma unroll
                    for (int kk = 0; kk < 2; kk++)
                        bfr[ni][kk] = *reinterpret_cast<const short8*>(bHalf + rbase + ni * 2048 + colk[kk]);
            }
            short8 afr[2][2];
            #pragma unroll
            for (int m2 = 0; m2 < 2; m2++)
                #pragma unroll
                for (int kk = 0; kk < 2; kk++)
                    afr[m2][kk] = *reinterpret_cast<const short8*>(aHalf + rbase + (q * 2 + m2) * 2048 + colk[kk]);
            if (q == 0 && t + 1 < nt) stageA(d ^ 1, 0, k0base + (t + 1) * BK);
            else if (q == 1 && t + 1 < nt) stageA(d ^ 1, 1, k0base + (t + 1) * BK);
            else if (q == 2 && t + 2 < nt) stageB(d, 0, k0base + (t + 2) * BK);
            else if (q == 3 && t + 2 < nt) stageB(d, 1, k0base + (t + 2) * BK);
            if (q == 3) {
                if (t + 2 < nt) asm volatile("s_waitcnt vmcnt(4)" ::: "memory");
                else            asm volatile("s_waitcnt vmcnt(0)" ::: "memory");
            }
            asm volatile("" ::: "memory");
            __builtin_amdgcn_s_barrier();
            asm volatile("" ::: "memory");
            __builtin_amdgcn_s_setprio(1);
            #pragma unroll
            for (int m2 = 0; m2 < 2; m2++)
                #pragma unroll
                for (int ni = 0; ni < 4; ni++)
                    #pragma unroll
                    for (int kk = 0; kk < 2; kk++)
                        acc[q * 2 + m2][ni] = __builtin_amdgcn_mfma_f32_16x16x32_bf16(
                            bfr[ni][kk], afr[m2][kk], acc[q * 2 + m2][ni], 0, 0, 0);
            __builtin_amdgcn_s_setprio(0);
            asm volatile("" ::: "memory");
            __builtin_amdgcn_s_barrier();
            asm volatile("" ::: "memory");
        }
    }

    // Swapped-D: row = bm0 + wr*128 + mi*16 + (l&15); cols = bn0 + wc*64 + ni*16 + (l>>4)*4 + reg
    int orow0 = bm0 + wr * 128, ocol0 = bn0 + wc * 64;
    const int lq = (l >> 4) * 4;
    #pragma unroll
    for (int mi = 0; mi < 8; mi++) {
        int row = orow0 + mi * 16 + lr;
        float scv = 0.0f;
        int iv = -1;
        if (EPI == 0) scv = sc[GATHER ? sel[row] : row];
        if (EPI == 3) iv = inv[row];
        #pragma unroll
        for (int ni = 0; ni < 4; ni++) {
            int c0 = ocol0 + ni * 16 + lq;
            if (EPI == 0) {
                f32x4 bv = *reinterpret_cast<const f32x4*>(bias + c0);
                u16x4 pk;
                #pragma unroll
                for (int rg = 0; rg < 4; rg++)
                    pk[rg] = f2bf(gelu_fast(fmaf(scv, acc[mi][ni][rg], bv[rg])));
                *reinterpret_cast<u16x4*>((unsigned short*)outb + (size_t)row * N + c0) = pk;
            } else if (EPI == 2) {
                u16x4 pk;
                #pragma unroll
                for (int rg = 0; rg < 4; rg++) pk[rg] = f2bf(acc[mi][ni][rg]);
                *reinterpret_cast<u16x4*>((unsigned short*)outb + ((size_t)bz * M + row) * (size_t)N + c0) = pk;
            } else {  // EPI == 3
                f32x4 bv = *reinterpret_cast<const f32x4*>(bias + c0);
                f32x4 v = acc[mi][ni] + bv;
                if (iv >= 0) {
                    f32x4 bv2 = *reinterpret_cast<const f32x4*>(bias2 + c0);
                    v = v + bv2;
                    for (int j = 0; j < nsk; j++) {
                        u16x4 p = *reinterpret_cast<const u16x4*>(phb + ((size_t)j * NSEL + iv) * DIMD + c0);
                        v[0] += bf2f(p[0]); v[1] += bf2f(p[1]);
                        v[2] += bf2f(p[2]); v[3] += bf2f(p[3]);
                    }
                }
                *reinterpret_cast<f32x4*>(outf + (size_t)row * N + c0) = v;
            }
        }
    }
}

extern "C" void kernel_launch(void* const* d_in, const int* in_sizes, int n_in,
                              void* d_out, int out_size, void* d_ws, size_t ws_size,
                              hipStream_t stream) {
    (void)in_sizes; (void)n_in; (void)out_size;
    const float* x      = (const float*)d_in[0];
    const float* rt     = (const float*)d_in[1];
    const float* lgamma = (const float*)d_in[2];
    const float* lw1    = (const float*)d_in[3];
    const float* lb1    = (const float*)d_in[4];
    const float* lw2    = (const float*)d_in[5];
    const float* lb2    = (const float*)d_in[6];
    const float* hgamma = (const float*)d_in[7];
    const float* hw1    = (const float*)d_in[8];
    const float* hb1    = (const float*)d_in[9];
    const float* hw2    = (const float*)d_in[10];
    const float* hb2    = (const float*)d_in[11];
    float* out = (float*)d_out;

    auto rnd = [](size_t b) { return (b + 255) & ~(size_t)255; };
    size_t fixed = rnd(NTOK * sizeof(double))        // s
                 + rnd(256)                          // a
                 + rnd(NSEL * sizeof(int))           // sel
                 + rnd(NTOK * sizeof(int))           // inv
                 + rnd(NTOK * sizeof(float))         // sc
                 + rnd((size_t)DLIGHT * DIMD * 2)    // wl1t
                 + rnd((size_t)DIMD * DLIGHT * 2)    // wl2t
                 + rnd((size_t)DHEAVY * DIMD * 2)    // wh1t
                 + rnd((size_t)DIMD * DHEAVY * 2)    // wh2t
                 + rnd((size_t)NTOK * DIMD * 2)      // xb
                 + rnd((size_t)NSEL * DHEAVY * 2);   // hh (aliased by hl)
    int nsk = 4;
    while (nsk > 1 && fixed + rnd((size_t)nsk * NSEL * DIMD * 2) > ws_size) nsk >>= 1;

    char* base = (char*)d_ws;
    size_t off = 0;
    auto alloc = [&](size_t bytes) -> void* {
        void* p = base + off;
        off += rnd(bytes);
        return p;
    };
    double* s     = (double*)alloc(NTOK * sizeof(double));
    double* a_arr = (double*)alloc(256);
    int*    sel   = (int*)alloc(NSEL * sizeof(int));
    int*    inv   = (int*)alloc(NTOK * sizeof(int));
    float*  sc    = (float*)alloc(NTOK * sizeof(float));
    short*  wl1t  = (short*)alloc((size_t)DLIGHT * DIMD * 2);
    short*  wl2t  = (short*)alloc((size_t)DIMD * DLIGHT * 2);
    short*  wh1t  = (short*)alloc((size_t)DHEAVY * DIMD * 2);
    short*  wh2t  = (short*)alloc((size_t)DIMD * DHEAVY * 2);
    short*  xb    = (short*)alloc((size_t)NTOK * DIMD * 2);
    short*  hh    = (short*)alloc((size_t)NSEL * DHEAVY * 2);
    short*  hl    = hh;  // light GEMM1 output aliases hh (dead after heavy GEMM2)
    short*  phb   = (short*)alloc((size_t)nsk * NSEL * DIMD * 2);

    // weights -> bf16 [N][K]; gamma folded into W1 rows
    cvt_transpose<<<dim3(DLIGHT / 32, DIMD / 32), dim3(32, 8), 0, stream>>>(lw1, (__hip_bfloat16*)wl1t, DIMD, DLIGHT, lgamma);
    cvt_transpose<<<dim3(DIMD / 32, DLIGHT / 32), dim3(32, 8), 0, stream>>>(lw2, (__hip_bfloat16*)wl2t, DLIGHT, DIMD, nullptr);
    cvt_transpose<<<dim3(DHEAVY / 32, DIMD / 32), dim3(32, 8), 0, stream>>>(hw1, (__hip_bfloat16*)wh1t, DIMD, DHEAVY, hgamma);
    cvt_transpose<<<dim3(DIMD / 32, DHEAVY / 32), dim3(32, 8), 0, stream>>>(hw2, (__hip_bfloat16*)wh2t, DHEAVY, DIMD, nullptr);

    hipMemsetAsync(inv, 0xFF, NTOK * sizeof(int), stream);  // inv = -1

    // fused pass: xb=bf16(x), sc, router s
    xpass_kern<<<NTOK, 256, 0, stream>>>(x, rt, (unsigned short*)xb, sc, s);
    descent_kern<<<NBATCH, 1024, 0, stream>>>(s, a_arr);
    select_kern<<<NBATCH, 64, 0, stream>>>(s, a_arr, sel, inv);

    // heavy: GEMM1 (gather rows of xb, sc+gelu epi) -> hh; GEMM2 split-K -> phb
    gemm256<0, true><<<dim3(DHEAVY / 256, NSEL / 256), 512, 0, stream>>>(
        xb, wh1t, hb1, nullptr, sc, sel, nullptr, nullptr, 0,
        nullptr, (__hip_bfloat16*)hh, NSEL, DHEAVY, DIMD);
    gemm256<2, false><<<dim3(DIMD / 256, NSEL / 256, nsk), 512, 0, stream>>>(
        hh, wh2t, nullptr, nullptr, nullptr, nullptr, nullptr, nullptr, 0,
        nullptr, (__hip_bfloat16*)phb, NSEL, DIMD, DHEAVY);

    // light: GEMM1 -> hl (aliases hh); GEMM2 fused (+hb2+phb partials via inv) -> out
    gemm256<0, false><<<dim3(DLIGHT / 256, NTOK / 256), 512, 0, stream>>>(
        xb, wl1t, lb1, nullptr, sc, nullptr, nullptr, nullptr, 0,
        nullptr, (__hip_bfloat16*)hl, NTOK, DLIGHT, DIMD);
    gemm256<3, false><<<dim3(DIMD / 256, NTOK / 256), 512, 0, stream>>>(
        hl, wl2t, lb2, hb2, nullptr, nullptr, inv, (const unsigned short*)phb, nsk,
        out, nullptr, NTOK, DIMD, DLIGHT);
}